// Round 5
// baseline (699.064 us; speedup 1.0000x reference)
//
#include <hip/hip_runtime.h>
#include <math.h>

#define NEG_SLOPE 0.2f

__device__ __forceinline__ float lrelu(float v) { return v > 0.0f ? v : NEG_SLOPE * v; }

// ---------------- CSR build ----------------

__global__ void count_dst_k(const int* __restrict__ dst, int* __restrict__ counts, int e) {
  int i = blockIdx.x * 256 + threadIdx.x;
  if (i < e) atomicAdd(&counts[dst[i]], 1);
}

// Hierarchical exclusive scan over counts (n elements, 256/block).
__global__ __launch_bounds__(256) void block_sum_k(const int* __restrict__ counts,
                                                   int* __restrict__ blockSums, int n) {
  int i = blockIdx.x * 256 + threadIdx.x;
  int v = (i < n) ? counts[i] : 0;
  for (int o = 32; o > 0; o >>= 1) v += __shfl_xor(v, o);
  __shared__ int ws[4];
  if ((threadIdx.x & 63) == 0) ws[threadIdx.x >> 6] = v;
  __syncthreads();
  if (threadIdx.x == 0) blockSums[blockIdx.x] = ws[0] + ws[1] + ws[2] + ws[3];
}

__global__ __launch_bounds__(256) void scan_sums_k(int* __restrict__ blockSums, int nb,
                                                   int* __restrict__ total_out) {
  __shared__ int sh[256];
  const int tid = threadIdx.x;
  int run = 0;
  for (int base = 0; base < nb; base += 256) {
    int i = base + tid;
    int v = (i < nb) ? blockSums[i] : 0;
    sh[tid] = v;
    __syncthreads();
    for (int o = 1; o < 256; o <<= 1) {
      int t = (tid >= o) ? sh[tid - o] : 0;
      __syncthreads();
      sh[tid] += t;
      __syncthreads();
    }
    int chunkTotal = sh[255];
    if (i < nb) blockSums[i] = run + sh[tid] - v;
    __syncthreads();
    run += chunkTotal;
  }
  if (tid == 0) *total_out = run;
}

__global__ __launch_bounds__(256) void scan_apply_k(int* __restrict__ counts_cursor,
                                                    const int* __restrict__ blockOffs,
                                                    int* __restrict__ row_ptr, int n) {
  __shared__ int sh[256];
  const int tid = threadIdx.x;
  const int i = blockIdx.x * 256 + tid;
  int v = (i < n) ? counts_cursor[i] : 0;
  sh[tid] = v;
  __syncthreads();
  for (int o = 1; o < 256; o <<= 1) {
    int t = (tid >= o) ? sh[tid - o] : 0;
    __syncthreads();
    sh[tid] += t;
    __syncthreads();
  }
  if (i < n) {
    int excl = blockOffs[blockIdx.x] + sh[tid] - v;
    row_ptr[i] = excl;
    counts_cursor[i] = excl;
  }
}

__global__ void scatter_k(const int* __restrict__ src, const int* __restrict__ dst,
                          int* __restrict__ cursor, int* __restrict__ csr, int e) {
  int i = blockIdx.x * 256 + threadIdx.x;
  if (i < e) {
    int pos = atomicAdd(&cursor[dst[i]], 1);
    csr[pos] = src[i];
  }
}

// ---------------- fused GEMM + attention coefficients ----------------
// Y[n,M] = X[n,128] @ W[128,M]; s/d = per-(row,head) dots with a_src/a_dst.
// 32 rows/block. X tile staged to LDS once (full K); W chunks (32 k) double-
// buffered in LDS with register prefetch of chunk kc+1 issued before the
// compute of chunk kc. One __syncthreads per chunk.

template<int M, int H_>
__global__ __launch_bounds__(256) void gemm_attn_k(const float* __restrict__ X,
                                                   const float* __restrict__ W,
                                                   const float* __restrict__ a_src,
                                                   const float* __restrict__ a_dst,
                                                   float* __restrict__ Y,
                                                   float* __restrict__ sArr,
                                                   float* __restrict__ dArr, int n) {
  constexpr int NC4 = M / 4;        // col quads: 32 (M=128) or 16 (M=64)
  constexpr int NTY = 256 / NC4;    // row groups: 8 or 16
  constexpr int RPT = 32 / NTY;     // rows per thread: 4 or 2
  constexpr int WCH = 32 * NC4;     // float4s per W chunk
  constexpr int WPT = WCH / 256;    // W float4s per thread per chunk: 4 or 2
  __shared__ float4 xs[32 * 32];    // [row][k4], full K=128 -> 16 KB
  __shared__ float4 wsb[2][WCH];    // double-buffered W chunk
  const int tid = threadIdx.x;
  const int tx = tid % NC4;
  const int ty = tid / NC4;
  const int rb = blockIdx.x * 32;

  // prologue: issue all X loads + W chunk 0
  float4 xr[4];
  for (int t = 0; t < 4; ++t) {
    int idx = tid + t * 256;
    int r = idx >> 5, k4 = idx & 31;
    int row = rb + r;
    xr[t] = (row < n) ? *(const float4*)(X + (size_t)row * 128 + k4 * 4)
                      : make_float4(0.f, 0.f, 0.f, 0.f);
  }
  float4 wr[WPT];
  for (int t = 0; t < WPT; ++t) wr[t] = ((const float4*)W)[tid + t * 256];
  for (int t = 0; t < 4; ++t) xs[tid + t * 256] = xr[t];
  for (int t = 0; t < WPT; ++t) wsb[0][tid + t * 256] = wr[t];
  __syncthreads();

  float acc[RPT][4];
  for (int i = 0; i < RPT; ++i)
    for (int j = 0; j < 4; ++j) acc[i][j] = 0.f;

  for (int kc = 0; kc < 4; ++kc) {
    if (kc < 3)
      for (int t = 0; t < WPT; ++t)
        wr[t] = ((const float4*)W)[(kc + 1) * WCH + tid + t * 256];
    const float4* wb = wsb[kc & 1];
    for (int k4 = 0; k4 < 8; ++k4) {
      float4 xv[RPT];
      for (int i = 0; i < RPT; ++i) xv[i] = xs[(ty + i * NTY) * 32 + kc * 8 + k4];
      float4 wv[4];
      for (int dk = 0; dk < 4; ++dk) wv[dk] = wb[(k4 * 4 + dk) * NC4 + tx];
      for (int i = 0; i < RPT; ++i) {
        acc[i][0] += xv[i].x * wv[0].x + xv[i].y * wv[1].x + xv[i].z * wv[2].x + xv[i].w * wv[3].x;
        acc[i][1] += xv[i].x * wv[0].y + xv[i].y * wv[1].y + xv[i].z * wv[2].y + xv[i].w * wv[3].y;
        acc[i][2] += xv[i].x * wv[0].z + xv[i].y * wv[1].z + xv[i].z * wv[2].z + xv[i].w * wv[3].z;
        acc[i][3] += xv[i].x * wv[0].w + xv[i].y * wv[1].w + xv[i].z * wv[2].w + xv[i].w * wv[3].w;
      }
    }
    if (kc < 3) {
      for (int t = 0; t < WPT; ++t) wsb[(kc + 1) & 1][tid + t * 256] = wr[t];
      __syncthreads();
    }
  }

  // epilogue: store Y and fused attention dots.
  // lane groups of 16 cover one (row, head) pair for both M=128 and M=64.
  const int lane = tid & 63;
  const float4 av = ((const float4*)a_src)[tx];
  const float4 dv = ((const float4*)a_dst)[tx];
  for (int i = 0; i < RPT; ++i) {
    int row = rb + ty + i * NTY;
    float s = acc[i][0] * av.x + acc[i][1] * av.y + acc[i][2] * av.z + acc[i][3] * av.w;
    float d = acc[i][0] * dv.x + acc[i][1] * dv.y + acc[i][2] * dv.z + acc[i][3] * dv.w;
    for (int o = 1; o < 16; o <<= 1) {
      s += __shfl_xor(s, o);
      d += __shfl_xor(d, o);
    }
    if (row < n) {
      *(float4*)(Y + (size_t)row * M + tx * 4) =
          make_float4(acc[i][0], acc[i][1], acc[i][2], acc[i][3]);
      if ((lane & 15) == 0) {
        int h = (H_ == 2) ? ((lane >> 4) & 1) : 0;
        sArr[row * H_ + h] = s;
        dArr[row * H_ + h] = d;
      }
    }
  }
}

// ---------------- softmax precompute ----------------

__global__ __launch_bounds__(256) void softmax2_k(const float* __restrict__ sArr,
                                                  const float* __restrict__ dArr,
                                                  const int* __restrict__ row_ptr,
                                                  const int* __restrict__ csr,
                                                  float* __restrict__ alphaE,
                                                  float* __restrict__ alphaSelf,
                                                  float* __restrict__ invArr, int n) {
  const int node = blockIdx.x * 4 + (threadIdx.x >> 6);
  const int lane = threadIdx.x & 63;
  if (node >= n) return;
  const int row = row_ptr[node];
  const int deg = row_ptr[node + 1] - row;
  const float2 dn = ((const float2*)dArr)[node];
  const float2 sn = ((const float2*)sArr)[node];
  const float e0s = lrelu(sn.x + dn.x), e1s = lrelu(sn.y + dn.y);
  float m0 = e0s, m1 = e1s;
  for (int j = lane; j < deg; j += 64) {
    int sj = csr[row + j];
    float2 sv = ((const float2*)sArr)[sj];
    m0 = fmaxf(m0, lrelu(sv.x + dn.x));
    m1 = fmaxf(m1, lrelu(sv.y + dn.y));
  }
  for (int o = 32; o > 0; o >>= 1) {
    m0 = fmaxf(m0, __shfl_xor(m0, o));
    m1 = fmaxf(m1, __shfl_xor(m1, o));
  }
  float s0 = 0.f, s1 = 0.f;
  for (int j = lane; j < deg; j += 64) {
    int sj = csr[row + j];
    float2 sv = ((const float2*)sArr)[sj];
    float x0 = __expf(lrelu(sv.x + dn.x) - m0);
    float x1 = __expf(lrelu(sv.y + dn.y) - m1);
    ((float2*)alphaE)[row + j] = make_float2(x0, x1);
    s0 += x0;
    s1 += x1;
  }
  for (int o = 32; o > 0; o >>= 1) {
    s0 += __shfl_xor(s0, o);
    s1 += __shfl_xor(s1, o);
  }
  float xs0 = __expf(e0s - m0), xs1 = __expf(e1s - m1);
  s0 += xs0;
  s1 += xs1;
  if (lane == 0) {
    ((float2*)alphaSelf)[node] = make_float2(xs0, xs1);
    ((float2*)invArr)[node] = make_float2(1.f / s0, 1.f / s1);
  }
}

__global__ __launch_bounds__(256) void softmax1_k(const float* __restrict__ sArr,
                                                  const float* __restrict__ dArr,
                                                  const int* __restrict__ row_ptr,
                                                  const int* __restrict__ csr,
                                                  float* __restrict__ alphaE,
                                                  float* __restrict__ alphaSelf,
                                                  float* __restrict__ invArr, int n) {
  const int node = blockIdx.x * 4 + (threadIdx.x >> 6);
  const int lane = threadIdx.x & 63;
  if (node >= n) return;
  const int row = row_ptr[node];
  const int deg = row_ptr[node + 1] - row;
  const float dn = dArr[node];
  const float es = lrelu(sArr[node] + dn);
  float m = es;
  for (int j = lane; j < deg; j += 64) {
    int sj = csr[row + j];
    m = fmaxf(m, lrelu(sArr[sj] + dn));
  }
  for (int o = 32; o > 0; o >>= 1) m = fmaxf(m, __shfl_xor(m, o));
  float s = 0.f;
  for (int j = lane; j < deg; j += 64) {
    int sj = csr[row + j];
    float x = __expf(lrelu(sArr[sj] + dn) - m);
    alphaE[row + j] = x;
    s += x;
  }
  for (int o = 32; o > 0; o >>= 1) s += __shfl_xor(s, o);
  float xs = __expf(es - m);
  s += xs;
  if (lane == 0) {
    alphaSelf[node] = xs;
    invArr[node] = 1.f / s;
  }
}

// ---------------- aggregation ----------------

template<bool DO_ELU>
__global__ __launch_bounds__(256) void aggr2_k(const float* __restrict__ xl,
                                               const float* __restrict__ alphaE,
                                               const float* __restrict__ alphaSelf,
                                               const float* __restrict__ invArr,
                                               const float* __restrict__ bias,
                                               const int* __restrict__ row_ptr,
                                               const int* __restrict__ csr,
                                               float* __restrict__ outp, int n) {
  const int node = blockIdx.x * 4 + (threadIdx.x >> 6);
  const int lane = threadIdx.x & 63;
  if (node >= n) return;
  const int row = row_ptr[node];
  const int deg = row_ptr[node + 1] - row;
  const float2* __restrict__ xl2 = (const float2*)xl;
  const float2* __restrict__ aE = (const float2*)alphaE;
  const bool lo = lane < 32;
  float ax = 0.f, ay = 0.f, bx = 0.f, by = 0.f;
  int j = 0;
  for (; j + 4 <= deg; j += 4) {
    int s0 = csr[row + j], s1 = csr[row + j + 1], s2 = csr[row + j + 2], s3 = csr[row + j + 3];
    float2 a0 = aE[row + j], a1 = aE[row + j + 1], a2 = aE[row + j + 2], a3 = aE[row + j + 3];
    float2 v0 = xl2[(size_t)s0 * 64 + lane];
    float2 v1 = xl2[(size_t)s1 * 64 + lane];
    float2 v2 = xl2[(size_t)s2 * 64 + lane];
    float2 v3 = xl2[(size_t)s3 * 64 + lane];
    float w0 = lo ? a0.x : a0.y, w1 = lo ? a1.x : a1.y;
    float w2 = lo ? a2.x : a2.y, w3 = lo ? a3.x : a3.y;
    ax += w0 * v0.x; ay += w0 * v0.y;
    bx += w1 * v1.x; by += w1 * v1.y;
    ax += w2 * v2.x; ay += w2 * v2.y;
    bx += w3 * v3.x; by += w3 * v3.y;
  }
  for (; j < deg; ++j) {
    int sj = csr[row + j];
    float2 a = aE[row + j];
    float2 v = xl2[(size_t)sj * 64 + lane];
    float w = lo ? a.x : a.y;
    ax += w * v.x; ay += w * v.y;
  }
  float2 aS = ((const float2*)alphaSelf)[node];
  float2 vS = xl2[(size_t)node * 64 + lane];
  float wS = lo ? aS.x : aS.y;
  ax += wS * vS.x; ay += wS * vS.y;
  float2 iv = ((const float2*)invArr)[node];
  float wi = lo ? iv.x : iv.y;
  float2 bb = ((const float2*)bias)[lane];
  float rx = (ax + bx) * wi + bb.x;
  float ry = (ay + by) * wi + bb.y;
  if (DO_ELU) {
    rx = rx > 0.f ? rx : expm1f(rx);
    ry = ry > 0.f ? ry : expm1f(ry);
  }
  ((float2*)outp)[(size_t)node * 64 + lane] = make_float2(rx, ry);
}

template<bool DO_ELU>
__global__ __launch_bounds__(256) void aggr1_k(const float* __restrict__ xl,
                                               const float* __restrict__ alphaE,
                                               const float* __restrict__ alphaSelf,
                                               const float* __restrict__ invArr,
                                               const float* __restrict__ bias,
                                               const int* __restrict__ row_ptr,
                                               const int* __restrict__ csr,
                                               float* __restrict__ outp, int n) {
  const int node = blockIdx.x * 4 + (threadIdx.x >> 6);
  const int lane = threadIdx.x & 63;
  if (node >= n) return;
  const int row = row_ptr[node];
  const int deg = row_ptr[node + 1] - row;
  float ax = 0.f, bx = 0.f;
  int j = 0;
  for (; j + 4 <= deg; j += 4) {
    int s0 = csr[row + j], s1 = csr[row + j + 1], s2 = csr[row + j + 2], s3 = csr[row + j + 3];
    float a0 = alphaE[row + j], a1 = alphaE[row + j + 1];
    float a2 = alphaE[row + j + 2], a3 = alphaE[row + j + 3];
    float v0 = xl[(size_t)s0 * 64 + lane];
    float v1 = xl[(size_t)s1 * 64 + lane];
    float v2 = xl[(size_t)s2 * 64 + lane];
    float v3 = xl[(size_t)s3 * 64 + lane];
    ax += a0 * v0; bx += a1 * v1;
    ax += a2 * v2; bx += a3 * v3;
  }
  for (; j < deg; ++j) {
    ax += alphaE[row + j] * xl[(size_t)csr[row + j] * 64 + lane];
  }
  float r = (ax + bx + alphaSelf[node] * xl[(size_t)node * 64 + lane]) * invArr[node] + bias[lane];
  if (DO_ELU) r = r > 0.f ? r : expm1f(r);
  outp[(size_t)node * 64 + lane] = r;
}

// ---------------- launch ----------------

extern "C" void kernel_launch(void* const* d_in, const int* in_sizes, int n_in,
                              void* d_out, int out_size, void* d_ws, size_t ws_size,
                              hipStream_t stream) {
  const float* x  = (const float*)d_in[0];
  const int* ei   = (const int*)d_in[1];
  const float* W0 = (const float*)d_in[2];
  const float* as0 = (const float*)d_in[3];
  const float* ad0 = (const float*)d_in[4];
  const float* b0 = (const float*)d_in[5];
  const float* W1 = (const float*)d_in[6];
  const float* as1 = (const float*)d_in[7];
  const float* ad1 = (const float*)d_in[8];
  const float* b1 = (const float*)d_in[9];
  const float* W2 = (const float*)d_in[10];
  const float* as2 = (const float*)d_in[11];
  const float* ad2 = (const float*)d_in[12];
  const float* b2 = (const float*)d_in[13];
  float* out = (float*)d_out;

  const int n = in_sizes[0] / 128;
  const int e = in_sizes[1] / 2;
  const int* srcIdx = ei;
  const int* dstIdx = ei + e;

  float* ws = (float*)d_ws;
  float* bufA = ws;                                 // n*128 (xl)
  float* bufB = bufA + (size_t)n * 128;             // n*128 (layer output)
  float* sArr = bufB + (size_t)n * 128;             // n*2
  float* dArr = sArr + (size_t)n * 2;               // n*2
  float* alphaSelf = dArr + (size_t)n * 2;          // n*2
  float* invArr = alphaSelf + (size_t)n * 2;        // n*2
  float* alphaE = invArr + (size_t)n * 2;           // e*2
  int* row_ptr = (int*)(alphaE + (size_t)e * 2);    // n+1
  int* cursor = row_ptr + (n + 1);                  // n
  int* csr = cursor + n;                            // e
  int* blockSums = csr + e;                         // nb

  const int nb = (n + 255) / 256;

  // CSR build (shared by all 3 layers)
  hipMemsetAsync(cursor, 0, (size_t)n * sizeof(int), stream);
  count_dst_k<<<(e + 255) / 256, 256, 0, stream>>>(dstIdx, cursor, e);
  block_sum_k<<<nb, 256, 0, stream>>>(cursor, blockSums, n);
  scan_sums_k<<<1, 256, 0, stream>>>(blockSums, nb, row_ptr + n);
  scan_apply_k<<<nb, 256, 0, stream>>>(cursor, blockSums, row_ptr, n);
  scatter_k<<<(e + 255) / 256, 256, 0, stream>>>(srcIdx, dstIdx, cursor, csr, e);

  const int gb = (n + 31) / 32;
  const int gp1 = (n + 3) / 4;

  // layer 0
  gemm_attn_k<128, 2><<<gb, 256, 0, stream>>>(x, W0, as0, ad0, bufA, sArr, dArr, n);
  softmax2_k<<<gp1, 256, 0, stream>>>(sArr, dArr, row_ptr, csr, alphaE, alphaSelf, invArr, n);
  aggr2_k<true><<<gp1, 256, 0, stream>>>(bufA, alphaE, alphaSelf, invArr, b0, row_ptr, csr, bufB, n);

  // layer 1
  gemm_attn_k<128, 2><<<gb, 256, 0, stream>>>(bufB, W1, as1, ad1, bufA, sArr, dArr, n);
  softmax2_k<<<gp1, 256, 0, stream>>>(sArr, dArr, row_ptr, csr, alphaE, alphaSelf, invArr, n);
  aggr2_k<true><<<gp1, 256, 0, stream>>>(bufA, alphaE, alphaSelf, invArr, b1, row_ptr, csr, bufB, n);

  // layer 2 (H=1, no concat, no elu)
  gemm_attn_k<64, 1><<<gb, 256, 0, stream>>>(bufB, W2, as2, ad2, bufA, sArr, dArr, n);
  softmax1_k<<<gp1, 256, 0, stream>>>(sArr, dArr, row_ptr, csr, alphaE, alphaSelf, invArr, n);
  aggr1_k<false><<<gp1, 256, 0, stream>>>(bufA, alphaE, alphaSelf, invArr, b2, row_ptr, csr, out, n);
}

// Round 6
// 537.203 us; speedup vs baseline: 1.3013x; 1.3013x over previous
//
#include <hip/hip_runtime.h>
#include <math.h>

#define NEG_SLOPE 0.2f

__device__ __forceinline__ float lrelu(float v) { return v > 0.0f ? v : NEG_SLOPE * v; }

// ---------------- CSR build ----------------

__global__ void count_dst_k(const int* __restrict__ dst, int* __restrict__ counts, int e) {
  int i = blockIdx.x * 256 + threadIdx.x;
  if (i < e) atomicAdd(&counts[dst[i]], 1);
}

__global__ __launch_bounds__(256) void block_sum_k(const int* __restrict__ counts,
                                                   int* __restrict__ blockSums, int n) {
  int i = blockIdx.x * 256 + threadIdx.x;
  int v = (i < n) ? counts[i] : 0;
  for (int o = 32; o > 0; o >>= 1) v += __shfl_xor(v, o);
  __shared__ int ws[4];
  if ((threadIdx.x & 63) == 0) ws[threadIdx.x >> 6] = v;
  __syncthreads();
  if (threadIdx.x == 0) blockSums[blockIdx.x] = ws[0] + ws[1] + ws[2] + ws[3];
}

__global__ __launch_bounds__(256) void scan_sums_k(int* __restrict__ blockSums, int nb,
                                                   int* __restrict__ total_out) {
  __shared__ int sh[256];
  const int tid = threadIdx.x;
  int run = 0;
  for (int base = 0; base < nb; base += 256) {
    int i = base + tid;
    int v = (i < nb) ? blockSums[i] : 0;
    sh[tid] = v;
    __syncthreads();
    for (int o = 1; o < 256; o <<= 1) {
      int t = (tid >= o) ? sh[tid - o] : 0;
      __syncthreads();
      sh[tid] += t;
      __syncthreads();
    }
    int chunkTotal = sh[255];
    if (i < nb) blockSums[i] = run + sh[tid] - v;
    __syncthreads();
    run += chunkTotal;
  }
  if (tid == 0) *total_out = run;
}

__global__ __launch_bounds__(256) void scan_apply_k(int* __restrict__ counts_cursor,
                                                    const int* __restrict__ blockOffs,
                                                    int* __restrict__ row_ptr, int n) {
  __shared__ int sh[256];
  const int tid = threadIdx.x;
  const int i = blockIdx.x * 256 + tid;
  int v = (i < n) ? counts_cursor[i] : 0;
  sh[tid] = v;
  __syncthreads();
  for (int o = 1; o < 256; o <<= 1) {
    int t = (tid >= o) ? sh[tid - o] : 0;
    __syncthreads();
    sh[tid] += t;
    __syncthreads();
  }
  if (i < n) {
    int excl = blockOffs[blockIdx.x] + sh[tid] - v;
    row_ptr[i] = excl;
    counts_cursor[i] = excl;
  }
}

__global__ void scatter_k(const int* __restrict__ src, const int* __restrict__ dst,
                          int* __restrict__ cursor, int* __restrict__ csr, int e) {
  int i = blockIdx.x * 256 + threadIdx.x;
  if (i < e) {
    int pos = atomicAdd(&cursor[dst[i]], 1);
    csr[pos] = src[i];
  }
}

// ---------------- GEMM (round-4 proven version): Y[n,M] = X[n,128] @ W[128,M] ----

template<int M>
__global__ __launch_bounds__(256) void gemm_k(const float* __restrict__ X,
                                              const float* __restrict__ W,
                                              float* __restrict__ Y, int n) {
  constexpr int NC4 = M / 4;
  constexpr int NTY = 256 / NC4;
  constexpr int RPT = 64 / NTY;
  __shared__ float4 ws4[32 * NC4];
  __shared__ float4 xs4[64 * 8];
  const int tid = threadIdx.x;
  const int tx = tid % NC4;
  const int ty = tid / NC4;
  const int rb = blockIdx.x * 64;
  float acc[RPT][4];
  for (int i = 0; i < RPT; ++i)
    for (int j = 0; j < 4; ++j) acc[i][j] = 0.f;

  for (int kc = 0; kc < 4; ++kc) {
    const float4* Wp = (const float4*)(W + (size_t)kc * 32 * M);
    for (int i = tid; i < 32 * NC4; i += 256) ws4[i] = Wp[i];
    for (int i = tid; i < 64 * 8; i += 256) {
      int r = i >> 3, c4 = i & 7;
      int row = rb + r;
      float4 v = make_float4(0.f, 0.f, 0.f, 0.f);
      if (row < n) v = *(const float4*)(X + (size_t)row * 128 + kc * 32 + c4 * 4);
      xs4[i] = v;
    }
    __syncthreads();
    for (int k4 = 0; k4 < 8; ++k4) {
      float4 xv[RPT];
      for (int i = 0; i < RPT; ++i) xv[i] = xs4[(ty + i * NTY) * 8 + k4];
      float4 wv[4];
      for (int dk = 0; dk < 4; ++dk) wv[dk] = ws4[(k4 * 4 + dk) * NC4 + tx];
      for (int i = 0; i < RPT; ++i) {
        acc[i][0] += xv[i].x * wv[0].x + xv[i].y * wv[1].x + xv[i].z * wv[2].x + xv[i].w * wv[3].x;
        acc[i][1] += xv[i].x * wv[0].y + xv[i].y * wv[1].y + xv[i].z * wv[2].y + xv[i].w * wv[3].y;
        acc[i][2] += xv[i].x * wv[0].z + xv[i].y * wv[1].z + xv[i].z * wv[2].z + xv[i].w * wv[3].z;
        acc[i][3] += xv[i].x * wv[0].w + xv[i].y * wv[1].w + xv[i].z * wv[2].w + xv[i].w * wv[3].w;
      }
    }
    __syncthreads();
  }
  for (int i = 0; i < RPT; ++i) {
    int row = rb + ty + i * NTY;
    if (row < n)
      *(float4*)(Y + (size_t)row * M + tx * 4) =
          make_float4(acc[i][0], acc[i][1], acc[i][2], acc[i][3]);
  }
}

// ---------------- attention coefficients: s/d per (node,head) ----------------

template<int H_>
__global__ __launch_bounds__(256) void attn_k(const float* __restrict__ xl,
                                              const float* __restrict__ a_src,
                                              const float* __restrict__ a_dst,
                                              float* __restrict__ sArr,
                                              float* __restrict__ dArr, int n) {
  const int pair = blockIdx.x * 4 + (threadIdx.x >> 6);
  const int lane = threadIdx.x & 63;
  if (pair >= n * H_) return;
  const int h = pair % H_;
  float v = xl[(size_t)pair * 64 + lane];
  float sv = v * a_src[h * 64 + lane];
  float dv = v * a_dst[h * 64 + lane];
  for (int o = 32; o > 0; o >>= 1) {
    sv += __shfl_xor(sv, o);
    dv += __shfl_xor(dv, o);
  }
  if (lane == 0) {
    sArr[pair] = sv;
    dArr[pair] = dv;
  }
}

// ---------------- fused softmax + aggregation: one wave per node ----------------
// No max-subtraction: e = lrelu(s+d) is O(10) for this model family, exp(e)
// cannot overflow fp32. Softmax is then linear until the final divide, so a
// single edge pass accumulates both the weighted sum and the denominator.
// H=2: lane loads float2 of the 512B xl row; lanes 0-31 = head0, 32-63 = head1.

template<bool DO_ELU>
__global__ __launch_bounds__(256) void edge2_k(const float* __restrict__ xl,
                                               const float* __restrict__ sArr,
                                               const float* __restrict__ dArr,
                                               const float* __restrict__ bias,
                                               const int* __restrict__ row_ptr,
                                               const int* __restrict__ csr,
                                               float* __restrict__ outp, int n) {
  const int node = blockIdx.x * 4 + (threadIdx.x >> 6);
  const int lane = threadIdx.x & 63;
  if (node >= n) return;
  const int row = row_ptr[node];
  const int deg = row_ptr[node + 1] - row;
  const float2* __restrict__ xl2 = (const float2*)xl;
  const float2* __restrict__ s2 = (const float2*)sArr;
  const float2 dn = ((const float2*)dArr)[node];
  const bool lo = lane < 32;
  float ax = 0.f, ay = 0.f, bx = 0.f, by = 0.f;
  float den0 = 0.f, den1 = 0.f;
  int j = 0;
  for (; j + 4 <= deg; j += 4) {
    int i0 = csr[row + j], i1 = csr[row + j + 1], i2 = csr[row + j + 2], i3 = csr[row + j + 3];
    float2 sv0 = s2[i0], sv1 = s2[i1], sv2 = s2[i2], sv3 = s2[i3];
    float2 v0 = xl2[(size_t)i0 * 64 + lane];
    float2 v1 = xl2[(size_t)i1 * 64 + lane];
    float2 v2 = xl2[(size_t)i2 * 64 + lane];
    float2 v3 = xl2[(size_t)i3 * 64 + lane];
    float w00 = __expf(lrelu(sv0.x + dn.x)), w01 = __expf(lrelu(sv0.y + dn.y));
    float w10 = __expf(lrelu(sv1.x + dn.x)), w11 = __expf(lrelu(sv1.y + dn.y));
    float w20 = __expf(lrelu(sv2.x + dn.x)), w21 = __expf(lrelu(sv2.y + dn.y));
    float w30 = __expf(lrelu(sv3.x + dn.x)), w31 = __expf(lrelu(sv3.y + dn.y));
    den0 += w00 + w10 + w20 + w30;
    den1 += w01 + w11 + w21 + w31;
    float u0 = lo ? w00 : w01, u1 = lo ? w10 : w11;
    float u2 = lo ? w20 : w21, u3 = lo ? w30 : w31;
    ax += u0 * v0.x; ay += u0 * v0.y;
    bx += u1 * v1.x; by += u1 * v1.y;
    ax += u2 * v2.x; ay += u2 * v2.y;
    bx += u3 * v3.x; by += u3 * v3.y;
  }
  for (; j < deg; ++j) {
    int i0 = csr[row + j];
    float2 sv = s2[i0];
    float2 v = xl2[(size_t)i0 * 64 + lane];
    float w0 = __expf(lrelu(sv.x + dn.x)), w1 = __expf(lrelu(sv.y + dn.y));
    den0 += w0;
    den1 += w1;
    float u = lo ? w0 : w1;
    ax += u * v.x; ay += u * v.y;
  }
  // self loop
  float2 sn = s2[node];
  float wS0 = __expf(lrelu(sn.x + dn.x)), wS1 = __expf(lrelu(sn.y + dn.y));
  den0 += wS0;
  den1 += wS1;
  float2 vS = xl2[(size_t)node * 64 + lane];
  float uS = lo ? wS0 : wS1;
  ax += uS * vS.x; ay += uS * vS.y;

  float wi = 1.f / (lo ? den0 : den1);
  float2 bb = ((const float2*)bias)[lane];
  float rx = (ax + bx) * wi + bb.x;
  float ry = (ay + by) * wi + bb.y;
  if (DO_ELU) {
    rx = rx > 0.f ? rx : expm1f(rx);
    ry = ry > 0.f ? ry : expm1f(ry);
  }
  ((float2*)outp)[(size_t)node * 64 + lane] = make_float2(rx, ry);
}

template<bool DO_ELU>
__global__ __launch_bounds__(256) void edge1_k(const float* __restrict__ xl,
                                               const float* __restrict__ sArr,
                                               const float* __restrict__ dArr,
                                               const float* __restrict__ bias,
                                               const int* __restrict__ row_ptr,
                                               const int* __restrict__ csr,
                                               float* __restrict__ outp, int n) {
  const int node = blockIdx.x * 4 + (threadIdx.x >> 6);
  const int lane = threadIdx.x & 63;
  if (node >= n) return;
  const int row = row_ptr[node];
  const int deg = row_ptr[node + 1] - row;
  const float dn = dArr[node];
  float ax = 0.f, bx = 0.f;
  float den = 0.f;
  int j = 0;
  for (; j + 4 <= deg; j += 4) {
    int i0 = csr[row + j], i1 = csr[row + j + 1], i2 = csr[row + j + 2], i3 = csr[row + j + 3];
    float s0 = sArr[i0], s1 = sArr[i1], s2v = sArr[i2], s3 = sArr[i3];
    float v0 = xl[(size_t)i0 * 64 + lane];
    float v1 = xl[(size_t)i1 * 64 + lane];
    float v2 = xl[(size_t)i2 * 64 + lane];
    float v3 = xl[(size_t)i3 * 64 + lane];
    float w0 = __expf(lrelu(s0 + dn)), w1 = __expf(lrelu(s1 + dn));
    float w2 = __expf(lrelu(s2v + dn)), w3 = __expf(lrelu(s3 + dn));
    den += w0 + w1 + w2 + w3;
    ax += w0 * v0; bx += w1 * v1;
    ax += w2 * v2; bx += w3 * v3;
  }
  for (; j < deg; ++j) {
    int i0 = csr[row + j];
    float w = __expf(lrelu(sArr[i0] + dn));
    den += w;
    ax += w * xl[(size_t)i0 * 64 + lane];
  }
  // self loop
  float wS = __expf(lrelu(sArr[node] + dn));
  den += wS;
  ax += wS * xl[(size_t)node * 64 + lane];

  float r = (ax + bx) / den + bias[lane];
  if (DO_ELU) r = r > 0.f ? r : expm1f(r);
  outp[(size_t)node * 64 + lane] = r;
}

// ---------------- launch ----------------

extern "C" void kernel_launch(void* const* d_in, const int* in_sizes, int n_in,
                              void* d_out, int out_size, void* d_ws, size_t ws_size,
                              hipStream_t stream) {
  const float* x  = (const float*)d_in[0];
  const int* ei   = (const int*)d_in[1];
  const float* W0 = (const float*)d_in[2];
  const float* as0 = (const float*)d_in[3];
  const float* ad0 = (const float*)d_in[4];
  const float* b0 = (const float*)d_in[5];
  const float* W1 = (const float*)d_in[6];
  const float* as1 = (const float*)d_in[7];
  const float* ad1 = (const float*)d_in[8];
  const float* b1 = (const float*)d_in[9];
  const float* W2 = (const float*)d_in[10];
  const float* as2 = (const float*)d_in[11];
  const float* ad2 = (const float*)d_in[12];
  const float* b2 = (const float*)d_in[13];
  float* out = (float*)d_out;

  const int n = in_sizes[0] / 128;
  const int e = in_sizes[1] / 2;
  const int* srcIdx = ei;
  const int* dstIdx = ei + e;

  float* ws = (float*)d_ws;
  float* bufA = ws;                                 // n*128 (xl)
  float* bufB = bufA + (size_t)n * 128;             // n*128 (layer output)
  float* sArr = bufB + (size_t)n * 128;             // n*2
  float* dArr = sArr + (size_t)n * 2;               // n*2
  int* row_ptr = (int*)(dArr + (size_t)n * 2);      // n+1
  int* cursor = row_ptr + (n + 1);                  // n
  int* csr = cursor + n;                            // e
  int* blockSums = csr + e;                         // nb

  const int nb = (n + 255) / 256;

  // CSR build (shared by all 3 layers)
  hipMemsetAsync(cursor, 0, (size_t)n * sizeof(int), stream);
  count_dst_k<<<(e + 255) / 256, 256, 0, stream>>>(dstIdx, cursor, e);
  block_sum_k<<<nb, 256, 0, stream>>>(cursor, blockSums, n);
  scan_sums_k<<<1, 256, 0, stream>>>(blockSums, nb, row_ptr + n);
  scan_apply_k<<<nb, 256, 0, stream>>>(cursor, blockSums, row_ptr, n);
  scatter_k<<<(e + 255) / 256, 256, 0, stream>>>(srcIdx, dstIdx, cursor, csr, e);

  const int gb = (n + 63) / 64;
  const int gp2 = (n * 2 + 3) / 4;  // (node,head) grid for attn H=2
  const int gp1 = (n + 3) / 4;      // node grid

  // layer 0
  gemm_k<128><<<gb, 256, 0, stream>>>(x, W0, bufA, n);
  attn_k<2><<<gp2, 256, 0, stream>>>(bufA, as0, ad0, sArr, dArr, n);
  edge2_k<true><<<gp1, 256, 0, stream>>>(bufA, sArr, dArr, b0, row_ptr, csr, bufB, n);

  // layer 1
  gemm_k<128><<<gb, 256, 0, stream>>>(bufB, W1, bufA, n);
  attn_k<2><<<gp2, 256, 0, stream>>>(bufA, as1, ad1, sArr, dArr, n);
  edge2_k<true><<<gp1, 256, 0, stream>>>(bufA, sArr, dArr, b1, row_ptr, csr, bufB, n);

  // layer 2 (H=1, no concat, no elu)
  gemm_k<64><<<gb, 256, 0, stream>>>(bufB, W2, bufA, n);
  attn_k<1><<<gp1, 256, 0, stream>>>(bufA, as2, ad2, sArr, dArr, n);
  edge1_k<false><<<gp1, 256, 0, stream>>>(bufA, sArr, dArr, b2, row_ptr, csr, out, n);
}

// Round 7
// 474.521 us; speedup vs baseline: 1.4732x; 1.1321x over previous
//
#include <hip/hip_runtime.h>
#include <hip/hip_fp16.h>
#include <math.h>

#define NEG_SLOPE 0.2f

__device__ __forceinline__ float lrelu(float v) { return v > 0.0f ? v : NEG_SLOPE * v; }

// ---------------- CSR build ----------------

__global__ void count_dst_k(const int* __restrict__ dst, int* __restrict__ counts, int e) {
  int i = blockIdx.x * 256 + threadIdx.x;
  if (i < e) atomicAdd(&counts[dst[i]], 1);
}

__global__ __launch_bounds__(256) void block_sum_k(const int* __restrict__ counts,
                                                   int* __restrict__ blockSums, int n) {
  int i = blockIdx.x * 256 + threadIdx.x;
  int v = (i < n) ? counts[i] : 0;
  for (int o = 32; o > 0; o >>= 1) v += __shfl_xor(v, o);
  __shared__ int ws[4];
  if ((threadIdx.x & 63) == 0) ws[threadIdx.x >> 6] = v;
  __syncthreads();
  if (threadIdx.x == 0) blockSums[blockIdx.x] = ws[0] + ws[1] + ws[2] + ws[3];
}

__global__ __launch_bounds__(256) void scan_sums_k(int* __restrict__ blockSums, int nb,
                                                   int* __restrict__ total_out) {
  __shared__ int sh[256];
  const int tid = threadIdx.x;
  int run = 0;
  for (int base = 0; base < nb; base += 256) {
    int i = base + tid;
    int v = (i < nb) ? blockSums[i] : 0;
    sh[tid] = v;
    __syncthreads();
    for (int o = 1; o < 256; o <<= 1) {
      int t = (tid >= o) ? sh[tid - o] : 0;
      __syncthreads();
      sh[tid] += t;
      __syncthreads();
    }
    int chunkTotal = sh[255];
    if (i < nb) blockSums[i] = run + sh[tid] - v;
    __syncthreads();
    run += chunkTotal;
  }
  if (tid == 0) *total_out = run;
}

__global__ __launch_bounds__(256) void scan_apply_k(int* __restrict__ counts_cursor,
                                                    const int* __restrict__ blockOffs,
                                                    int* __restrict__ row_ptr, int n) {
  __shared__ int sh[256];
  const int tid = threadIdx.x;
  const int i = blockIdx.x * 256 + tid;
  int v = (i < n) ? counts_cursor[i] : 0;
  sh[tid] = v;
  __syncthreads();
  for (int o = 1; o < 256; o <<= 1) {
    int t = (tid >= o) ? sh[tid - o] : 0;
    __syncthreads();
    sh[tid] += t;
    __syncthreads();
  }
  if (i < n) {
    int excl = blockOffs[blockIdx.x] + sh[tid] - v;
    row_ptr[i] = excl;
    counts_cursor[i] = excl;
  }
}

// scatter also records the dst node per CSR slot (needed by alpha kernels)
__global__ void scatter_k(const int* __restrict__ src, const int* __restrict__ dst,
                          int* __restrict__ cursor, int* __restrict__ csr,
                          int* __restrict__ edgeDst, int e) {
  int i = blockIdx.x * 256 + threadIdx.x;
  if (i < e) {
    int d = dst[i];
    int pos = atomicAdd(&cursor[d], 1);
    csr[pos] = src[i];
    edgeDst[pos] = d;
  }
}

// ---------------- GEMM: Yh[n,LDM](fp16) = X[n,128] @ W[128,LDM], 64x64 tiles ----
// Round-4 proven pipeline; columns split across blockIdx.y for 2x grid and
// 17 KB LDS (8 blocks/CU co-resident -> phase stalls hidden across blocks).

template<int LDM>
__global__ __launch_bounds__(256) void gemm64_k(const float* __restrict__ X,
                                                const float* __restrict__ W,
                                                __half* __restrict__ Yh, int n) {
  constexpr int LDM4 = LDM / 4;
  __shared__ float4 ws4[32 * 16];  // [k_in_chunk][colquad]
  __shared__ float4 xs4[64 * 9];   // [row][k4], padded 8->9 (bank spread)
  const int tid = threadIdx.x;
  const int tx = tid & 15;   // col quad 0..15
  const int ty = tid >> 4;   // 0..15
  const int rb = blockIdx.x * 64;
  const int coff4 = blockIdx.y * 16;
  float acc[4][4];
  for (int i = 0; i < 4; ++i)
    for (int j = 0; j < 4; ++j) acc[i][j] = 0.f;

  for (int kc = 0; kc < 4; ++kc) {
    const float4* Wp = (const float4*)W + (size_t)(kc * 32) * LDM4;
    for (int i = tid; i < 32 * 16; i += 256) {
      int k = i >> 4, q = i & 15;
      ws4[i] = Wp[(size_t)k * LDM4 + coff4 + q];
    }
    for (int i = tid; i < 64 * 8; i += 256) {
      int r = i >> 3, c4 = i & 7;
      int row = rb + r;
      float4 v = make_float4(0.f, 0.f, 0.f, 0.f);
      if (row < n) v = *(const float4*)(X + (size_t)row * 128 + kc * 32 + c4 * 4);
      xs4[r * 9 + c4] = v;
    }
    __syncthreads();
    for (int k4 = 0; k4 < 8; ++k4) {
      float4 xv[4];
      for (int i = 0; i < 4; ++i) xv[i] = xs4[(ty + i * 16) * 9 + k4];
      float4 wv[4];
      for (int dk = 0; dk < 4; ++dk) wv[dk] = ws4[(k4 * 4 + dk) * 16 + tx];
      for (int i = 0; i < 4; ++i) {
        acc[i][0] += xv[i].x * wv[0].x + xv[i].y * wv[1].x + xv[i].z * wv[2].x + xv[i].w * wv[3].x;
        acc[i][1] += xv[i].x * wv[0].y + xv[i].y * wv[1].y + xv[i].z * wv[2].y + xv[i].w * wv[3].y;
        acc[i][2] += xv[i].x * wv[0].z + xv[i].y * wv[1].z + xv[i].z * wv[2].z + xv[i].w * wv[3].z;
        acc[i][3] += xv[i].x * wv[0].w + xv[i].y * wv[1].w + xv[i].z * wv[2].w + xv[i].w * wv[3].w;
      }
    }
    __syncthreads();
  }
  for (int i = 0; i < 4; ++i) {
    int row = rb + ty + i * 16;
    if (row < n) {
      __half2 h01 = __floats2half2_rn(acc[i][0], acc[i][1]);
      __half2 h23 = __floats2half2_rn(acc[i][2], acc[i][3]);
      uint2 pk;
      pk.x = *(unsigned int*)&h01;
      pk.y = *(unsigned int*)&h23;
      *(uint2*)(Yh + (size_t)row * LDM + blockIdx.y * 64 + tx * 4) = pk;
    }
  }
}

// ---------------- attention coefficients: s/d per (node,head) ----------------

template<int H_>
__global__ __launch_bounds__(256) void attn_k(const __half* __restrict__ xlh,
                                              const float* __restrict__ a_src,
                                              const float* __restrict__ a_dst,
                                              float* __restrict__ sArr,
                                              float* __restrict__ dArr, int n) {
  const int pair = blockIdx.x * 4 + (threadIdx.x >> 6);
  const int lane = threadIdx.x & 63;
  if (pair >= n * H_) return;
  const int h = pair % H_;
  float v = __half2float(xlh[(size_t)pair * 64 + lane]);
  float sv = v * a_src[h * 64 + lane];
  float dv = v * a_dst[h * 64 + lane];
  for (int o = 32; o > 0; o >>= 1) {
    sv += __shfl_xor(sv, o);
    dv += __shfl_xor(dv, o);
  }
  if (lane == 0) {
    sArr[pair] = sv;
    dArr[pair] = dv;
  }
}

// ---------------- per-edge unnormalized weights (edge-parallel, no 64x redundancy) --

__global__ __launch_bounds__(256) void alpha2_k(const float* __restrict__ sArr,
                                                const float* __restrict__ dArr,
                                                const int* __restrict__ csr,
                                                const int* __restrict__ edgeDst,
                                                float* __restrict__ alphaE, int e) {
  int i = blockIdx.x * 256 + threadIdx.x;
  if (i < e) {
    int s = csr[i], d = edgeDst[i];
    float2 sv = ((const float2*)sArr)[s];
    float2 dv = ((const float2*)dArr)[d];
    ((float2*)alphaE)[i] =
        make_float2(__expf(lrelu(sv.x + dv.x)), __expf(lrelu(sv.y + dv.y)));
  }
}

__global__ __launch_bounds__(256) void alpha1_k(const float* __restrict__ sArr,
                                                const float* __restrict__ dArr,
                                                const int* __restrict__ csr,
                                                const int* __restrict__ edgeDst,
                                                float* __restrict__ alphaE, int e) {
  int i = blockIdx.x * 256 + threadIdx.x;
  if (i < e) {
    alphaE[i] = __expf(lrelu(sArr[csr[i]] + dArr[edgeDst[i]]));
  }
}

// ---------------- aggregation: one wave per node, fp16 xl gather ----------------
// Softmax denominator accumulated alongside (linear until final divide).
// H=2: lane loads half2 (4B) of the 256B fp16 row; lanes 0-31 head0, 32-63 head1.

template<bool DO_ELU>
__global__ __launch_bounds__(256) void edge2h_k(const __half* __restrict__ xlh,
                                                const float* __restrict__ sArr,
                                                const float* __restrict__ dArr,
                                                const float* __restrict__ alphaE,
                                                const float* __restrict__ bias,
                                                const int* __restrict__ row_ptr,
                                                const int* __restrict__ csr,
                                                float* __restrict__ outp, int n) {
  const int node = blockIdx.x * 4 + (threadIdx.x >> 6);
  const int lane = threadIdx.x & 63;
  if (node >= n) return;
  const int row = row_ptr[node];
  const int deg = row_ptr[node + 1] - row;
  const unsigned int* __restrict__ xlu = (const unsigned int*)xlh;
  const float2* __restrict__ aE = (const float2*)alphaE;
  const bool lo = lane < 32;
  float ax = 0.f, ay = 0.f, bx = 0.f, by = 0.f;
  float den0 = 0.f, den1 = 0.f;
  int j = 0;
  for (; j + 4 <= deg; j += 4) {
    int i0 = csr[row + j], i1 = csr[row + j + 1], i2 = csr[row + j + 2], i3 = csr[row + j + 3];
    float2 a0 = aE[row + j], a1 = aE[row + j + 1], a2 = aE[row + j + 2], a3 = aE[row + j + 3];
    unsigned int p0 = xlu[(size_t)i0 * 64 + lane];
    unsigned int p1 = xlu[(size_t)i1 * 64 + lane];
    unsigned int p2 = xlu[(size_t)i2 * 64 + lane];
    unsigned int p3 = xlu[(size_t)i3 * 64 + lane];
    float2 v0 = __half22float2(*(__half2*)&p0);
    float2 v1 = __half22float2(*(__half2*)&p1);
    float2 v2 = __half22float2(*(__half2*)&p2);
    float2 v3 = __half22float2(*(__half2*)&p3);
    den0 += a0.x + a1.x + a2.x + a3.x;
    den1 += a0.y + a1.y + a2.y + a3.y;
    float u0 = lo ? a0.x : a0.y, u1 = lo ? a1.x : a1.y;
    float u2 = lo ? a2.x : a2.y, u3 = lo ? a3.x : a3.y;
    ax += u0 * v0.x; ay += u0 * v0.y;
    bx += u1 * v1.x; by += u1 * v1.y;
    ax += u2 * v2.x; ay += u2 * v2.y;
    bx += u3 * v3.x; by += u3 * v3.y;
  }
  for (; j < deg; ++j) {
    int i0 = csr[row + j];
    float2 a = aE[row + j];
    unsigned int p = xlu[(size_t)i0 * 64 + lane];
    float2 v = __half22float2(*(__half2*)&p);
    den0 += a.x;
    den1 += a.y;
    float u = lo ? a.x : a.y;
    ax += u * v.x; ay += u * v.y;
  }
  // self loop
  const float2 dn = ((const float2*)dArr)[node];
  const float2 sn = ((const float2*)sArr)[node];
  float wS0 = __expf(lrelu(sn.x + dn.x)), wS1 = __expf(lrelu(sn.y + dn.y));
  den0 += wS0;
  den1 += wS1;
  unsigned int pS = xlu[(size_t)node * 64 + lane];
  float2 vS = __half22float2(*(__half2*)&pS);
  float uS = lo ? wS0 : wS1;
  ax += uS * vS.x; ay += uS * vS.y;

  float wi = 1.f / (lo ? den0 : den1);
  float2 bb = ((const float2*)bias)[lane];
  float rx = (ax + bx) * wi + bb.x;
  float ry = (ay + by) * wi + bb.y;
  if (DO_ELU) {
    rx = rx > 0.f ? rx : expm1f(rx);
    ry = ry > 0.f ? ry : expm1f(ry);
  }
  ((float2*)outp)[(size_t)node * 64 + lane] = make_float2(rx, ry);
}

template<bool DO_ELU>
__global__ __launch_bounds__(256) void edge1h_k(const __half* __restrict__ xlh,
                                                const float* __restrict__ sArr,
                                                const float* __restrict__ dArr,
                                                const float* __restrict__ alphaE,
                                                const float* __restrict__ bias,
                                                const int* __restrict__ row_ptr,
                                                const int* __restrict__ csr,
                                                float* __restrict__ outp, int n) {
  const int node = blockIdx.x * 4 + (threadIdx.x >> 6);
  const int lane = threadIdx.x & 63;
  if (node >= n) return;
  const int row = row_ptr[node];
  const int deg = row_ptr[node + 1] - row;
  float ax = 0.f, bx = 0.f;
  float den = 0.f;
  int j = 0;
  for (; j + 4 <= deg; j += 4) {
    int i0 = csr[row + j], i1 = csr[row + j + 1], i2 = csr[row + j + 2], i3 = csr[row + j + 3];
    float a0 = alphaE[row + j], a1 = alphaE[row + j + 1];
    float a2 = alphaE[row + j + 2], a3 = alphaE[row + j + 3];
    float v0 = __half2float(xlh[(size_t)i0 * 64 + lane]);
    float v1 = __half2float(xlh[(size_t)i1 * 64 + lane]);
    float v2 = __half2float(xlh[(size_t)i2 * 64 + lane]);
    float v3 = __half2float(xlh[(size_t)i3 * 64 + lane]);
    den += a0 + a1 + a2 + a3;
    ax += a0 * v0; bx += a1 * v1;
    ax += a2 * v2; bx += a3 * v3;
  }
  for (; j < deg; ++j) {
    float a = alphaE[row + j];
    den += a;
    ax += a * __half2float(xlh[(size_t)csr[row + j] * 64 + lane]);
  }
  // self loop
  float wS = __expf(lrelu(sArr[node] + dArr[node]));
  den += wS;
  ax += wS * __half2float(xlh[(size_t)node * 64 + lane]);

  float r = (ax + bx) / den + bias[lane];
  if (DO_ELU) r = r > 0.f ? r : expm1f(r);
  outp[(size_t)node * 64 + lane] = r;
}

// ---------------- launch ----------------

extern "C" void kernel_launch(void* const* d_in, const int* in_sizes, int n_in,
                              void* d_out, int out_size, void* d_ws, size_t ws_size,
                              hipStream_t stream) {
  const float* x  = (const float*)d_in[0];
  const int* ei   = (const int*)d_in[1];
  const float* W0 = (const float*)d_in[2];
  const float* as0 = (const float*)d_in[3];
  const float* ad0 = (const float*)d_in[4];
  const float* b0 = (const float*)d_in[5];
  const float* W1 = (const float*)d_in[6];
  const float* as1 = (const float*)d_in[7];
  const float* ad1 = (const float*)d_in[8];
  const float* b1 = (const float*)d_in[9];
  const float* W2 = (const float*)d_in[10];
  const float* as2 = (const float*)d_in[11];
  const float* ad2 = (const float*)d_in[12];
  const float* b2 = (const float*)d_in[13];
  float* out = (float*)d_out;

  const int n = in_sizes[0] / 128;
  const int e = in_sizes[1] / 2;
  const int* srcIdx = ei;
  const int* dstIdx = ei + e;

  float* ws = (float*)d_ws;
  float* bufB = ws;                                 // n*128 fp32 (layer output)
  float* sArr = bufB + (size_t)n * 128;             // n*2
  float* dArr = sArr + (size_t)n * 2;               // n*2
  float* alphaE = dArr + (size_t)n * 2;             // e*2
  float* xl_region = alphaE + (size_t)e * 2;        // n*128 halves = n*64 floats
  __half* xlh = (__half*)xl_region;
  int* row_ptr = (int*)(xl_region + (size_t)n * 64);  // n+1
  int* cursor = row_ptr + (n + 1);                  // n
  int* csr = cursor + n;                            // e
  int* edgeDst = csr + e;                           // e
  int* blockSums = edgeDst + e;                     // nb

  const int nb = (n + 255) / 256;
  const int ge = (e + 255) / 256;

  // CSR build (shared by all 3 layers)
  hipMemsetAsync(cursor, 0, (size_t)n * sizeof(int), stream);
  count_dst_k<<<ge, 256, 0, stream>>>(dstIdx, cursor, e);
  block_sum_k<<<nb, 256, 0, stream>>>(cursor, blockSums, n);
  scan_sums_k<<<1, 256, 0, stream>>>(blockSums, nb, row_ptr + n);
  scan_apply_k<<<nb, 256, 0, stream>>>(cursor, blockSums, row_ptr, n);
  scatter_k<<<ge, 256, 0, stream>>>(srcIdx, dstIdx, cursor, csr, edgeDst, e);

  const int gb = (n + 63) / 64;
  const int gp2 = (n * 2 + 3) / 4;
  const int gp1 = (n + 3) / 4;

  // layer 0
  gemm64_k<128><<<dim3(gb, 2), 256, 0, stream>>>(x, W0, xlh, n);
  attn_k<2><<<gp2, 256, 0, stream>>>(xlh, as0, ad0, sArr, dArr, n);
  alpha2_k<<<ge, 256, 0, stream>>>(sArr, dArr, csr, edgeDst, alphaE, e);
  edge2h_k<true><<<gp1, 256, 0, stream>>>(xlh, sArr, dArr, alphaE, b0, row_ptr, csr, bufB, n);

  // layer 1
  gemm64_k<128><<<dim3(gb, 2), 256, 0, stream>>>(bufB, W1, xlh, n);
  attn_k<2><<<gp2, 256, 0, stream>>>(xlh, as1, ad1, sArr, dArr, n);
  alpha2_k<<<ge, 256, 0, stream>>>(sArr, dArr, csr, edgeDst, alphaE, e);
  edge2h_k<true><<<gp1, 256, 0, stream>>>(xlh, sArr, dArr, alphaE, b1, row_ptr, csr, bufB, n);

  // layer 2 (H=1, no concat, no elu)
  gemm64_k<64><<<dim3(gb, 1), 256, 0, stream>>>(bufB, W2, xlh, n);
  attn_k<1><<<gp1, 256, 0, stream>>>(xlh, as2, ad2, sArr, dArr, n);
  alpha1_k<<<ge, 256, 0, stream>>>(sArr, dArr, csr, edgeDst, alphaE, e);
  edge1h_k<false><<<gp1, 256, 0, stream>>>(xlh, sArr, dArr, alphaE, b2, row_ptr, csr, out, n);
}

// Round 8
// 411.413 us; speedup vs baseline: 1.6992x; 1.1534x over previous
//
#include <hip/hip_runtime.h>
#include <hip/hip_fp16.h>
#include <math.h>

#define NEG_SLOPE 0.2f

__device__ __forceinline__ float lrelu(float v) { return v > 0.0f ? v : NEG_SLOPE * v; }

typedef _Float16 half8 __attribute__((ext_vector_type(8)));
typedef float floatx4 __attribute__((ext_vector_type(4)));

// ---------------- CSR build ----------------

__global__ void count_dst_k(const int* __restrict__ dst, int* __restrict__ counts, int e) {
  int i = blockIdx.x * 256 + threadIdx.x;
  if (i < e) atomicAdd(&counts[dst[i]], 1);
}

__global__ __launch_bounds__(256) void block_sum_k(const int* __restrict__ counts,
                                                   int* __restrict__ blockSums, int n) {
  int i = blockIdx.x * 256 + threadIdx.x;
  int v = (i < n) ? counts[i] : 0;
  for (int o = 32; o > 0; o >>= 1) v += __shfl_xor(v, o);
  __shared__ int ws[4];
  if ((threadIdx.x & 63) == 0) ws[threadIdx.x >> 6] = v;
  __syncthreads();
  if (threadIdx.x == 0) blockSums[blockIdx.x] = ws[0] + ws[1] + ws[2] + ws[3];
}

__global__ __launch_bounds__(256) void scan_sums_k(int* __restrict__ blockSums, int nb,
                                                   int* __restrict__ total_out) {
  __shared__ int sh[256];
  const int tid = threadIdx.x;
  int run = 0;
  for (int base = 0; base < nb; base += 256) {
    int i = base + tid;
    int v = (i < nb) ? blockSums[i] : 0;
    sh[tid] = v;
    __syncthreads();
    for (int o = 1; o < 256; o <<= 1) {
      int t = (tid >= o) ? sh[tid - o] : 0;
      __syncthreads();
      sh[tid] += t;
      __syncthreads();
    }
    int chunkTotal = sh[255];
    if (i < nb) blockSums[i] = run + sh[tid] - v;
    __syncthreads();
    run += chunkTotal;
  }
  if (tid == 0) *total_out = run;
}

__global__ __launch_bounds__(256) void scan_apply_k(int* __restrict__ counts_cursor,
                                                    const int* __restrict__ blockOffs,
                                                    int* __restrict__ row_ptr, int n) {
  __shared__ int sh[256];
  const int tid = threadIdx.x;
  const int i = blockIdx.x * 256 + tid;
  int v = (i < n) ? counts_cursor[i] : 0;
  sh[tid] = v;
  __syncthreads();
  for (int o = 1; o < 256; o <<= 1) {
    int t = (tid >= o) ? sh[tid - o] : 0;
    __syncthreads();
    sh[tid] += t;
    __syncthreads();
  }
  if (i < n) {
    int excl = blockOffs[blockIdx.x] + sh[tid] - v;
    row_ptr[i] = excl;
    counts_cursor[i] = excl;
  }
}

// scatter packed (src,dst) as one 8B store per edge (one cacheline touch, not two)
__global__ void scatter_k(const int* __restrict__ src, const int* __restrict__ dst,
                          int* __restrict__ cursor, int2* __restrict__ csrPair, int e) {
  int i = blockIdx.x * 256 + threadIdx.x;
  if (i < e) {
    int d = dst[i];
    int pos = atomicAdd(&cursor[d], 1);
    csrPair[pos] = make_int2(src[i], d);
  }
}

// ---------------- dtype converts (once per launch) ----------------

__global__ __launch_bounds__(256) void cvt_f2h_k(const float* __restrict__ src,
                                                 __half* __restrict__ dst, int count4) {
  int i = blockIdx.x * 256 + threadIdx.x;
  if (i < count4) {
    float4 v = ((const float4*)src)[i];
    __half2 a = __floats2half2_rn(v.x, v.y);
    __half2 b = __floats2half2_rn(v.z, v.w);
    uint2 pk;
    pk.x = *(unsigned int*)&a;
    pk.y = *(unsigned int*)&b;
    ((uint2*)dst)[i] = pk;
  }
}

// W[k][col] fp32 -> Wt[col][k] fp16 (transposed, tiny)
__global__ __launch_bounds__(256) void cvt_wt_k(const float* __restrict__ W,
                                                __half* __restrict__ Wt, int M) {
  int i = blockIdx.x * 256 + threadIdx.x;
  if (i < M * 128) {
    int col = i >> 7, k = i & 127;
    Wt[i] = __float2half(W[k * M + col]);
  }
}

// ---------------- MFMA GEMM: Yh[n,M] = Xh[n,128] @ W, fp16 in / fp16 out ----------
// 64 rows/block, 4 waves; wave w computes rows w*16..w*16+15, all M cols.
// Xs/Ws row pitch 136 halves (272B): bank step 4, worst 2-way conflict (free).
// A frag: X[m=lane&15][k=kq*32+quad*8+j]; B frag: Wt[col=ct*16+lane&15][same k];
// D: row=quad*4+reg, col=lane&15 (m89-verified mapping).

template<int M>
__global__ __launch_bounds__(256) void gemm_mfma_k(const __half* __restrict__ Xh,
                                                   const __half* __restrict__ Wt,
                                                   __half* __restrict__ Yh, int n) {
  constexpr int CT = M / 16;  // col tiles per wave: 8 or 4
  constexpr int LP = 136;     // LDS row pitch in halves
  __shared__ _Float16 Xs[64 * LP];
  __shared__ _Float16 Ws[M * LP];
  const int tid = threadIdx.x;
  const int w = tid >> 6;
  const int lane = tid & 63;
  const int l15 = lane & 15;
  const int quad = lane >> 4;
  const int rb = blockIdx.x * 64;

  for (int t = 0; t < 4; ++t) {
    int idx = tid + t * 256;  // 64 rows x 16 groups of 8 halves
    int r = idx >> 4, c8 = idx & 15;
    uint4 v = make_uint4(0, 0, 0, 0);
    if (rb + r < n) v = *(const uint4*)(Xh + (size_t)(rb + r) * 128 + c8 * 8);
    *(uint4*)&Xs[r * LP + c8 * 8] = v;
  }
  for (int t = 0; t < CT; ++t) {
    int idx = tid + t * 256;  // M rows x 16 groups
    int r = idx >> 4, c8 = idx & 15;
    *(uint4*)&Ws[r * LP + c8 * 8] = *(const uint4*)(Wt + (size_t)r * 128 + c8 * 8);
  }
  __syncthreads();

  floatx4 acc[CT];
  for (int c = 0; c < CT; ++c)
    for (int j = 0; j < 4; ++j) acc[c][j] = 0.f;

  const int arow = w * 16 + l15;
  for (int kq = 0; kq < 4; ++kq) {
    half8 a = *(const half8*)&Xs[arow * LP + kq * 32 + quad * 8];
    for (int c = 0; c < CT; ++c) {
      half8 b = *(const half8*)&Ws[(c * 16 + l15) * LP + kq * 32 + quad * 8];
      acc[c] = __builtin_amdgcn_mfma_f32_16x16x32_f16(a, b, acc[c], 0, 0, 0);
    }
  }

  for (int c = 0; c < CT; ++c) {
    for (int r = 0; r < 4; ++r) {
      int row = rb + w * 16 + quad * 4 + r;
      if (row < n) Yh[(size_t)row * M + c * 16 + l15] = __float2half(acc[c][r]);
    }
  }
}

// ---------------- attention coefficients: s/d per (node,head) ----------------

template<int H_>
__global__ __launch_bounds__(256) void attn_k(const __half* __restrict__ xlh,
                                              const float* __restrict__ a_src,
                                              const float* __restrict__ a_dst,
                                              float* __restrict__ sArr,
                                              float* __restrict__ dArr, int n) {
  const int pair = blockIdx.x * 4 + (threadIdx.x >> 6);
  const int lane = threadIdx.x & 63;
  if (pair >= n * H_) return;
  const int h = pair % H_;
  float v = __half2float(xlh[(size_t)pair * 64 + lane]);
  float sv = v * a_src[h * 64 + lane];
  float dv = v * a_dst[h * 64 + lane];
  for (int o = 32; o > 0; o >>= 1) {
    sv += __shfl_xor(sv, o);
    dv += __shfl_xor(dv, o);
  }
  if (lane == 0) {
    sArr[pair] = sv;
    dArr[pair] = dv;
  }
}

// ---------------- per-edge unnormalized weights ----------------

__global__ __launch_bounds__(256) void alpha2_k(const float* __restrict__ sArr,
                                                const float* __restrict__ dArr,
                                                const int2* __restrict__ csrPair,
                                                float* __restrict__ alphaE, int e) {
  int i = blockIdx.x * 256 + threadIdx.x;
  if (i < e) {
    int2 p = csrPair[i];
    float2 sv = ((const float2*)sArr)[p.x];
    float2 dv = ((const float2*)dArr)[p.y];
    ((float2*)alphaE)[i] =
        make_float2(__expf(lrelu(sv.x + dv.x)), __expf(lrelu(sv.y + dv.y)));
  }
}

__global__ __launch_bounds__(256) void alpha1_k(const float* __restrict__ sArr,
                                                const float* __restrict__ dArr,
                                                const int2* __restrict__ csrPair,
                                                float* __restrict__ alphaE, int e) {
  int i = blockIdx.x * 256 + threadIdx.x;
  if (i < e) {
    int2 p = csrPair[i];
    alphaE[i] = __expf(lrelu(sArr[p.x] + dArr[p.y]));
  }
}

// ---------------- aggregation: one wave per node, fp16 xl gather ----------------

__global__ __launch_bounds__(256) void edge2h_k(const __half* __restrict__ xlh,
                                                const float* __restrict__ sArr,
                                                const float* __restrict__ dArr,
                                                const float* __restrict__ alphaE,
                                                const float* __restrict__ bias,
                                                const int* __restrict__ row_ptr,
                                                const int2* __restrict__ csrPair,
                                                __half* __restrict__ outh, int n) {
  const int node = blockIdx.x * 4 + (threadIdx.x >> 6);
  const int lane = threadIdx.x & 63;
  if (node >= n) return;
  const int row = row_ptr[node];
  const int deg = row_ptr[node + 1] - row;
  const unsigned int* __restrict__ xlu = (const unsigned int*)xlh;
  const float2* __restrict__ aE = (const float2*)alphaE;
  const bool lo = lane < 32;
  float ax = 0.f, ay = 0.f, bx = 0.f, by = 0.f;
  float den0 = 0.f, den1 = 0.f;
  int j = 0;
  for (; j + 4 <= deg; j += 4) {
    int i0 = csrPair[row + j].x, i1 = csrPair[row + j + 1].x;
    int i2 = csrPair[row + j + 2].x, i3 = csrPair[row + j + 3].x;
    float2 a0 = aE[row + j], a1 = aE[row + j + 1], a2 = aE[row + j + 2], a3 = aE[row + j + 3];
    unsigned int p0 = xlu[(size_t)i0 * 64 + lane];
    unsigned int p1 = xlu[(size_t)i1 * 64 + lane];
    unsigned int p2 = xlu[(size_t)i2 * 64 + lane];
    unsigned int p3 = xlu[(size_t)i3 * 64 + lane];
    float2 v0 = __half22float2(*(__half2*)&p0);
    float2 v1 = __half22float2(*(__half2*)&p1);
    float2 v2 = __half22float2(*(__half2*)&p2);
    float2 v3 = __half22float2(*(__half2*)&p3);
    den0 += a0.x + a1.x + a2.x + a3.x;
    den1 += a0.y + a1.y + a2.y + a3.y;
    float u0 = lo ? a0.x : a0.y, u1 = lo ? a1.x : a1.y;
    float u2 = lo ? a2.x : a2.y, u3 = lo ? a3.x : a3.y;
    ax += u0 * v0.x; ay += u0 * v0.y;
    bx += u1 * v1.x; by += u1 * v1.y;
    ax += u2 * v2.x; ay += u2 * v2.y;
    bx += u3 * v3.x; by += u3 * v3.y;
  }
  for (; j < deg; ++j) {
    int i0 = csrPair[row + j].x;
    float2 a = aE[row + j];
    unsigned int p = xlu[(size_t)i0 * 64 + lane];
    float2 v = __half22float2(*(__half2*)&p);
    den0 += a.x;
    den1 += a.y;
    float u = lo ? a.x : a.y;
    ax += u * v.x; ay += u * v.y;
  }
  const float2 dn = ((const float2*)dArr)[node];
  const float2 sn = ((const float2*)sArr)[node];
  float wS0 = __expf(lrelu(sn.x + dn.x)), wS1 = __expf(lrelu(sn.y + dn.y));
  den0 += wS0;
  den1 += wS1;
  unsigned int pS = xlu[(size_t)node * 64 + lane];
  float2 vS = __half22float2(*(__half2*)&pS);
  float uS = lo ? wS0 : wS1;
  ax += uS * vS.x; ay += uS * vS.y;

  float wi = 1.f / (lo ? den0 : den1);
  float2 bb = ((const float2*)bias)[lane];
  float rx = (ax + bx) * wi + bb.x;
  float ry = (ay + by) * wi + bb.y;
  rx = rx > 0.f ? rx : expm1f(rx);  // ELU (both H=2 layers use it)
  ry = ry > 0.f ? ry : expm1f(ry);
  __half2 o = __floats2half2_rn(rx, ry);
  ((__half2*)outh)[(size_t)node * 64 + lane] = o;
}

__global__ __launch_bounds__(256) void edge1h_k(const __half* __restrict__ xlh,
                                                const float* __restrict__ sArr,
                                                const float* __restrict__ dArr,
                                                const float* __restrict__ alphaE,
                                                const float* __restrict__ bias,
                                                const int* __restrict__ row_ptr,
                                                const int2* __restrict__ csrPair,
                                                float* __restrict__ outp, int n) {
  const int node = blockIdx.x * 4 + (threadIdx.x >> 6);
  const int lane = threadIdx.x & 63;
  if (node >= n) return;
  const int row = row_ptr[node];
  const int deg = row_ptr[node + 1] - row;
  float ax = 0.f, bx = 0.f;
  float den = 0.f;
  int j = 0;
  for (; j + 4 <= deg; j += 4) {
    int i0 = csrPair[row + j].x, i1 = csrPair[row + j + 1].x;
    int i2 = csrPair[row + j + 2].x, i3 = csrPair[row + j + 3].x;
    float a0 = alphaE[row + j], a1 = alphaE[row + j + 1];
    float a2 = alphaE[row + j + 2], a3 = alphaE[row + j + 3];
    float v0 = __half2float(xlh[(size_t)i0 * 64 + lane]);
    float v1 = __half2float(xlh[(size_t)i1 * 64 + lane]);
    float v2 = __half2float(xlh[(size_t)i2 * 64 + lane]);
    float v3 = __half2float(xlh[(size_t)i3 * 64 + lane]);
    den += a0 + a1 + a2 + a3;
    ax += a0 * v0; bx += a1 * v1;
    ax += a2 * v2; bx += a3 * v3;
  }
  for (; j < deg; ++j) {
    float a = alphaE[row + j];
    den += a;
    ax += a * __half2float(xlh[(size_t)csrPair[row + j].x * 64 + lane]);
  }
  float wS = __expf(lrelu(sArr[node] + dArr[node]));
  den += wS;
  ax += wS * __half2float(xlh[(size_t)node * 64 + lane]);

  float r = (ax + bx) / den + bias[lane];
  outp[(size_t)node * 64 + lane] = r;
}

// ---------------- launch ----------------

extern "C" void kernel_launch(void* const* d_in, const int* in_sizes, int n_in,
                              void* d_out, int out_size, void* d_ws, size_t ws_size,
                              hipStream_t stream) {
  const float* x  = (const float*)d_in[0];
  const int* ei   = (const int*)d_in[1];
  const float* W0 = (const float*)d_in[2];
  const float* as0 = (const float*)d_in[3];
  const float* ad0 = (const float*)d_in[4];
  const float* b0 = (const float*)d_in[5];
  const float* W1 = (const float*)d_in[6];
  const float* as1 = (const float*)d_in[7];
  const float* ad1 = (const float*)d_in[8];
  const float* b1 = (const float*)d_in[9];
  const float* W2 = (const float*)d_in[10];
  const float* as2 = (const float*)d_in[11];
  const float* ad2 = (const float*)d_in[12];
  const float* b2 = (const float*)d_in[13];
  float* out = (float*)d_out;

  const int n = in_sizes[0] / 128;
  const int e = in_sizes[1] / 2;
  const int* srcIdx = ei;
  const int* dstIdx = ei + e;

  float* ws = (float*)d_ws;
  float* sArr = ws;                                  // n*2
  float* dArr = sArr + (size_t)n * 2;                // n*2
  float* alphaE = dArr + (size_t)n * 2;              // e*2
  __half* xlh = (__half*)(alphaE + (size_t)e * 2);   // n*128 halves
  __half* bufHh = xlh + (size_t)n * 128;             // n*128 halves
  __half* Wt0 = bufHh + (size_t)n * 128;             // 128*128
  __half* Wt1 = Wt0 + 128 * 128;                     // 128*128
  __half* Wt2 = Wt1 + 128 * 128;                     // 64*128
  int2* csrPair = (int2*)(Wt2 + 64 * 128);           // e pairs
  int* row_ptr = (int*)(csrPair + e);                // n+1
  int* cursor = row_ptr + (n + 1);                   // n
  int* blockSums = cursor + n;                       // nb

  const int nb = (n + 255) / 256;
  const int ge = (e + 255) / 256;

  // converts (tiny) + CSR build
  cvt_wt_k<<<(128 * 128 + 255) / 256, 256, 0, stream>>>(W0, Wt0, 128);
  cvt_wt_k<<<(128 * 128 + 255) / 256, 256, 0, stream>>>(W1, Wt1, 128);
  cvt_wt_k<<<(64 * 128 + 255) / 256, 256, 0, stream>>>(W2, Wt2, 64);
  cvt_f2h_k<<<((n * 32) + 255) / 256, 256, 0, stream>>>(x, bufHh, n * 32);

  hipMemsetAsync(cursor, 0, (size_t)n * sizeof(int), stream);
  count_dst_k<<<ge, 256, 0, stream>>>(dstIdx, cursor, e);
  block_sum_k<<<nb, 256, 0, stream>>>(cursor, blockSums, n);
  scan_sums_k<<<1, 256, 0, stream>>>(blockSums, nb, row_ptr + n);
  scan_apply_k<<<nb, 256, 0, stream>>>(cursor, blockSums, row_ptr, n);
  scatter_k<<<ge, 256, 0, stream>>>(srcIdx, dstIdx, cursor, csrPair, e);

  const int gb = (n + 63) / 64;
  const int gp2 = (n * 2 + 3) / 4;
  const int gp1 = (n + 3) / 4;

  // layer 0 (input fp16 in bufHh; edge output overwrites bufHh afterwards)
  gemm_mfma_k<128><<<gb, 256, 0, stream>>>(bufHh, Wt0, xlh, n);
  attn_k<2><<<gp2, 256, 0, stream>>>(xlh, as0, ad0, sArr, dArr, n);
  alpha2_k<<<ge, 256, 0, stream>>>(sArr, dArr, csrPair, alphaE, e);
  edge2h_k<<<gp1, 256, 0, stream>>>(xlh, sArr, dArr, alphaE, b0, row_ptr, csrPair, bufHh, n);

  // layer 1
  gemm_mfma_k<128><<<gb, 256, 0, stream>>>(bufHh, Wt1, xlh, n);
  attn_k<2><<<gp2, 256, 0, stream>>>(xlh, as1, ad1, sArr, dArr, n);
  alpha2_k<<<ge, 256, 0, stream>>>(sArr, dArr, csrPair, alphaE, e);
  edge2h_k<<<gp1, 256, 0, stream>>>(xlh, sArr, dArr, alphaE, b1, row_ptr, csrPair, bufHh, n);

  // layer 2 (H=1, no concat, no elu, fp32 out)
  gemm_mfma_k<64><<<gb, 256, 0, stream>>>(bufHh, Wt2, xlh, n);
  attn_k<1><<<gp1, 256, 0, stream>>>(xlh, as2, ad2, sArr, dArr, n);
  alpha1_k<<<ge, 256, 0, stream>>>(sArr, dArr, csrPair, alphaE, e);
  edge1h_k<<<gp1, 256, 0, stream>>>(xlh, sArr, dArr, alphaE, b2, row_ptr, csrPair, out, n);
}

// Round 9
// 381.545 us; speedup vs baseline: 1.8322x; 1.0783x over previous
//
#include <hip/hip_runtime.h>
#include <hip/hip_fp16.h>
#include <math.h>

#define NEG_SLOPE 0.2f

__device__ __forceinline__ float lrelu(float v) { return v > 0.0f ? v : NEG_SLOPE * v; }

typedef _Float16 half8 __attribute__((ext_vector_type(8)));
typedef float floatx4 __attribute__((ext_vector_type(4)));

// ---------------- CSR build ----------------

__global__ void count_dst_k(const int* __restrict__ dst, int* __restrict__ counts, int e) {
  int i = blockIdx.x * 256 + threadIdx.x;
  if (i < e) atomicAdd(&counts[dst[i]], 1);
}

__global__ __launch_bounds__(256) void block_sum_k(const int* __restrict__ counts,
                                                   int* __restrict__ blockSums, int n) {
  int i = blockIdx.x * 256 + threadIdx.x;
  int v = (i < n) ? counts[i] : 0;
  for (int o = 32; o > 0; o >>= 1) v += __shfl_xor(v, o);
  __shared__ int ws[4];
  if ((threadIdx.x & 63) == 0) ws[threadIdx.x >> 6] = v;
  __syncthreads();
  if (threadIdx.x == 0) blockSums[blockIdx.x] = ws[0] + ws[1] + ws[2] + ws[3];
}

__global__ __launch_bounds__(256) void scan_sums_k(int* __restrict__ blockSums, int nb,
                                                   int* __restrict__ total_out) {
  __shared__ int sh[256];
  const int tid = threadIdx.x;
  int run = 0;
  for (int base = 0; base < nb; base += 256) {
    int i = base + tid;
    int v = (i < nb) ? blockSums[i] : 0;
    sh[tid] = v;
    __syncthreads();
    for (int o = 1; o < 256; o <<= 1) {
      int t = (tid >= o) ? sh[tid - o] : 0;
      __syncthreads();
      sh[tid] += t;
      __syncthreads();
    }
    int chunkTotal = sh[255];
    if (i < nb) blockSums[i] = run + sh[tid] - v;
    __syncthreads();
    run += chunkTotal;
  }
  if (tid == 0) *total_out = run;
}

__global__ __launch_bounds__(256) void scan_apply_k(int* __restrict__ counts_cursor,
                                                    const int* __restrict__ blockOffs,
                                                    int* __restrict__ row_ptr, int n) {
  __shared__ int sh[256];
  const int tid = threadIdx.x;
  const int i = blockIdx.x * 256 + tid;
  int v = (i < n) ? counts_cursor[i] : 0;
  sh[tid] = v;
  __syncthreads();
  for (int o = 1; o < 256; o <<= 1) {
    int t = (tid >= o) ? sh[tid - o] : 0;
    __syncthreads();
    sh[tid] += t;
    __syncthreads();
  }
  if (i < n) {
    int excl = blockOffs[blockIdx.x] + sh[tid] - v;
    row_ptr[i] = excl;
    counts_cursor[i] = excl;
  }
}

__global__ void scatter_k(const int* __restrict__ src, const int* __restrict__ dst,
                          int* __restrict__ cursor, int2* __restrict__ csrPair, int e) {
  int i = blockIdx.x * 256 + threadIdx.x;
  if (i < e) {
    int d = dst[i];
    int pos = atomicAdd(&cursor[d], 1);
    csrPair[pos] = make_int2(src[i], d);
  }
}

// ---------------- dtype converts (once per launch) ----------------

__global__ __launch_bounds__(256) void cvt_f2h_k(const float* __restrict__ src,
                                                 __half* __restrict__ dst, int count4) {
  int i = blockIdx.x * 256 + threadIdx.x;
  if (i < count4) {
    float4 v = ((const float4*)src)[i];
    __half2 a = __floats2half2_rn(v.x, v.y);
    __half2 b = __floats2half2_rn(v.z, v.w);
    uint2 pk;
    pk.x = *(unsigned int*)&a;
    pk.y = *(unsigned int*)&b;
    ((uint2*)dst)[i] = pk;
  }
}

// All three W[k][col] fp32 -> Wt[col][k] fp16 transposes in one kernel.
__global__ __launch_bounds__(256) void cvt_wt3_k(const float* __restrict__ W0,
                                                 const float* __restrict__ W1,
                                                 const float* __restrict__ W2,
                                                 __half* __restrict__ Wt0,
                                                 __half* __restrict__ Wt1,
                                                 __half* __restrict__ Wt2) {
  int i = blockIdx.x * 256 + threadIdx.x;
  if (i < 128 * 128) {
    int col = i >> 7, k = i & 127;
    Wt0[i] = __float2half(W0[k * 128 + col]);
    Wt1[i] = __float2half(W1[k * 128 + col]);
    if (col < 64) Wt2[(size_t)col * 128 + k] = __float2half(W2[k * 64 + col]);
  }
}

// ---------------- MFMA GEMM + fused attention dots ----------------
// Yh[n,M] = Xh[n,128] @ W (fp16 in/out); epilogue computes per-(row,head)
// s = <xl_row, a_src_h>, d = <xl_row, a_dst_h> from the fp32 accumulators.
// 64 rows/block, 4 waves; wave w owns rows w*16..w*16+15, all M cols.
// acc[c][r] = D[row=w*16+quad*4+r][col=c*16+l15]; head h = c>>2 (M=128) or 0.

template<int M, int H_>
__global__ __launch_bounds__(256) void gemm_attn_mfma_k(const __half* __restrict__ Xh,
                                                        const __half* __restrict__ Wt,
                                                        const float* __restrict__ a_src,
                                                        const float* __restrict__ a_dst,
                                                        __half* __restrict__ Yh,
                                                        float* __restrict__ sArr,
                                                        float* __restrict__ dArr, int n) {
  constexpr int CT = M / 16;
  constexpr int LP = 136;  // LDS row pitch in halves (272B: 2-way conflict = free)
  __shared__ _Float16 Xs[64 * LP];
  __shared__ _Float16 Ws[M * LP];
  const int tid = threadIdx.x;
  const int w = tid >> 6;
  const int lane = tid & 63;
  const int l15 = lane & 15;
  const int quad = lane >> 4;
  const int rb = blockIdx.x * 64;

  for (int t = 0; t < 4; ++t) {
    int idx = tid + t * 256;
    int r = idx >> 4, c8 = idx & 15;
    uint4 v = make_uint4(0, 0, 0, 0);
    if (rb + r < n) v = *(const uint4*)(Xh + (size_t)(rb + r) * 128 + c8 * 8);
    *(uint4*)&Xs[r * LP + c8 * 8] = v;
  }
  for (int t = 0; t < CT; ++t) {
    int idx = tid + t * 256;
    int r = idx >> 4, c8 = idx & 15;
    *(uint4*)&Ws[r * LP + c8 * 8] = *(const uint4*)(Wt + (size_t)r * 128 + c8 * 8);
  }
  __syncthreads();

  floatx4 acc[CT];
  for (int c = 0; c < CT; ++c)
    for (int j = 0; j < 4; ++j) acc[c][j] = 0.f;

  const int arow = w * 16 + l15;
  for (int kq = 0; kq < 4; ++kq) {
    half8 a = *(const half8*)&Xs[arow * LP + kq * 32 + quad * 8];
    for (int c = 0; c < CT; ++c) {
      half8 b = *(const half8*)&Ws[(c * 16 + l15) * LP + kq * 32 + quad * 8];
      acc[c] = __builtin_amdgcn_mfma_f32_16x16x32_f16(a, b, acc[c], 0, 0, 0);
    }
  }

  // attention vectors per owned column
  float as[CT], ad[CT];
  for (int c = 0; c < CT; ++c) {
    as[c] = a_src[c * 16 + l15];
    ad[c] = a_dst[c * 16 + l15];
  }

  for (int c = 0; c < CT; ++c) {
    for (int r = 0; r < 4; ++r) {
      int row = rb + w * 16 + quad * 4 + r;
      if (row < n) Yh[(size_t)row * M + c * 16 + l15] = __float2half(acc[c][r]);
    }
  }

  // fused attn dots: per r, head sums over owned cols, then 16-lane reduce
  for (int r = 0; r < 4; ++r) {
    int row = rb + w * 16 + quad * 4 + r;
    float s0 = 0.f, d0 = 0.f, s1 = 0.f, d1 = 0.f;
    if (H_ == 2) {
      for (int c = 0; c < CT / 2; ++c) {
        s0 += acc[c][r] * as[c];
        d0 += acc[c][r] * ad[c];
      }
      for (int c = CT / 2; c < CT; ++c) {
        s1 += acc[c][r] * as[c];
        d1 += acc[c][r] * ad[c];
      }
    } else {
      for (int c = 0; c < CT; ++c) {
        s0 += acc[c][r] * as[c];
        d0 += acc[c][r] * ad[c];
      }
    }
    for (int o = 1; o < 16; o <<= 1) {
      s0 += __shfl_xor(s0, o);
      d0 += __shfl_xor(d0, o);
      if (H_ == 2) {
        s1 += __shfl_xor(s1, o);
        d1 += __shfl_xor(d1, o);
      }
    }
    if (l15 == 0 && row < n) {
      if (H_ == 2) {
        sArr[row * 2] = s0;
        sArr[row * 2 + 1] = s1;
        dArr[row * 2] = d0;
        dArr[row * 2 + 1] = d1;
      } else {
        sArr[row] = s0;
        dArr[row] = d0;
      }
    }
  }
}

// ---------------- per-edge unnormalized weights ----------------

__global__ __launch_bounds__(256) void alpha2_k(const float* __restrict__ sArr,
                                                const float* __restrict__ dArr,
                                                const int2* __restrict__ csrPair,
                                                float* __restrict__ alphaE, int e) {
  int i = blockIdx.x * 256 + threadIdx.x;
  if (i < e) {
    int2 p = csrPair[i];
    float2 sv = ((const float2*)sArr)[p.x];
    float2 dv = ((const float2*)dArr)[p.y];
    ((float2*)alphaE)[i] =
        make_float2(__expf(lrelu(sv.x + dv.x)), __expf(lrelu(sv.y + dv.y)));
  }
}

__global__ __launch_bounds__(256) void alpha1_k(const float* __restrict__ sArr,
                                                const float* __restrict__ dArr,
                                                const int2* __restrict__ csrPair,
                                                float* __restrict__ alphaE, int e) {
  int i = blockIdx.x * 256 + threadIdx.x;
  if (i < e) {
    int2 p = csrPair[i];
    alphaE[i] = __expf(lrelu(sArr[p.x] + dArr[p.y]));
  }
}

// ---------------- aggregation: one wave per node, fp16 gather, 8-deep MLP ----------

__global__ __launch_bounds__(256) void edge2h_k(const __half* __restrict__ xlh,
                                                const float* __restrict__ sArr,
                                                const float* __restrict__ dArr,
                                                const float* __restrict__ alphaE,
                                                const float* __restrict__ bias,
                                                const int* __restrict__ row_ptr,
                                                const int2* __restrict__ csrPair,
                                                __half* __restrict__ outh, int n) {
  const int node = blockIdx.x * 4 + (threadIdx.x >> 6);
  const int lane = threadIdx.x & 63;
  if (node >= n) return;
  const int row = row_ptr[node];
  const int deg = row_ptr[node + 1] - row;
  const unsigned int* __restrict__ xlu = (const unsigned int*)xlh;
  const float2* __restrict__ aE = (const float2*)alphaE;
  const bool lo = lane < 32;
  float ax = 0.f, ay = 0.f;
  float den0 = 0.f, den1 = 0.f;
  int j = 0;
  for (; j + 8 <= deg; j += 8) {
    int idx[8];
    float2 a[8];
    unsigned int p[8];
    for (int t = 0; t < 8; ++t) idx[t] = csrPair[row + j + t].x;
    for (int t = 0; t < 8; ++t) a[t] = aE[row + j + t];
    for (int t = 0; t < 8; ++t) p[t] = xlu[(size_t)idx[t] * 64 + lane];
    for (int t = 0; t < 8; ++t) {
      den0 += a[t].x;
      den1 += a[t].y;
      float2 v = __half22float2(*(__half2*)&p[t]);
      float u = lo ? a[t].x : a[t].y;
      ax += u * v.x;
      ay += u * v.y;
    }
  }
  for (; j < deg; ++j) {
    int i0 = csrPair[row + j].x;
    float2 a = aE[row + j];
    unsigned int p = xlu[(size_t)i0 * 64 + lane];
    float2 v = __half22float2(*(__half2*)&p);
    den0 += a.x;
    den1 += a.y;
    float u = lo ? a.x : a.y;
    ax += u * v.x;
    ay += u * v.y;
  }
  const float2 dn = ((const float2*)dArr)[node];
  const float2 sn = ((const float2*)sArr)[node];
  float wS0 = __expf(lrelu(sn.x + dn.x)), wS1 = __expf(lrelu(sn.y + dn.y));
  den0 += wS0;
  den1 += wS1;
  unsigned int pS = xlu[(size_t)node * 64 + lane];
  float2 vS = __half22float2(*(__half2*)&pS);
  float uS = lo ? wS0 : wS1;
  ax += uS * vS.x;
  ay += uS * vS.y;

  float wi = 1.f / (lo ? den0 : den1);
  float2 bb = ((const float2*)bias)[lane];
  float rx = ax * wi + bb.x;
  float ry = ay * wi + bb.y;
  rx = rx > 0.f ? rx : expm1f(rx);
  ry = ry > 0.f ? ry : expm1f(ry);
  __half2 o = __floats2half2_rn(rx, ry);
  ((__half2*)outh)[(size_t)node * 64 + lane] = o;
}

__global__ __launch_bounds__(256) void edge1h_k(const __half* __restrict__ xlh,
                                                const float* __restrict__ sArr,
                                                const float* __restrict__ dArr,
                                                const float* __restrict__ alphaE,
                                                const float* __restrict__ bias,
                                                const int* __restrict__ row_ptr,
                                                const int2* __restrict__ csrPair,
                                                float* __restrict__ outp, int n) {
  const int node = blockIdx.x * 4 + (threadIdx.x >> 6);
  const int lane = threadIdx.x & 63;
  if (node >= n) return;
  const int row = row_ptr[node];
  const int deg = row_ptr[node + 1] - row;
  float ax = 0.f;
  float den = 0.f;
  int j = 0;
  for (; j + 8 <= deg; j += 8) {
    int idx[8];
    float a[8];
    __half v[8];
    for (int t = 0; t < 8; ++t) idx[t] = csrPair[row + j + t].x;
    for (int t = 0; t < 8; ++t) a[t] = alphaE[row + j + t];
    for (int t = 0; t < 8; ++t) v[t] = xlh[(size_t)idx[t] * 64 + lane];
    for (int t = 0; t < 8; ++t) {
      den += a[t];
      ax += a[t] * __half2float(v[t]);
    }
  }
  for (; j < deg; ++j) {
    float a = alphaE[row + j];
    den += a;
    ax += a * __half2float(xlh[(size_t)csrPair[row + j].x * 64 + lane]);
  }
  float wS = __expf(lrelu(sArr[node] + dArr[node]));
  den += wS;
  ax += wS * __half2float(xlh[(size_t)node * 64 + lane]);

  float r = ax / den + bias[lane];
  outp[(size_t)node * 64 + lane] = r;
}

// ---------------- launch ----------------

extern "C" void kernel_launch(void* const* d_in, const int* in_sizes, int n_in,
                              void* d_out, int out_size, void* d_ws, size_t ws_size,
                              hipStream_t stream) {
  const float* x  = (const float*)d_in[0];
  const int* ei   = (const int*)d_in[1];
  const float* W0 = (const float*)d_in[2];
  const float* as0 = (const float*)d_in[3];
  const float* ad0 = (const float*)d_in[4];
  const float* b0 = (const float*)d_in[5];
  const float* W1 = (const float*)d_in[6];
  const float* as1 = (const float*)d_in[7];
  const float* ad1 = (const float*)d_in[8];
  const float* b1 = (const float*)d_in[9];
  const float* W2 = (const float*)d_in[10];
  const float* as2 = (const float*)d_in[11];
  const float* ad2 = (const float*)d_in[12];
  const float* b2 = (const float*)d_in[13];
  float* out = (float*)d_out;

  const int n = in_sizes[0] / 128;
  const int e = in_sizes[1] / 2;
  const int* srcIdx = ei;
  const int* dstIdx = ei + e;

  float* ws = (float*)d_ws;
  float* sArr = ws;                                  // n*2
  float* dArr = sArr + (size_t)n * 2;                // n*2
  float* alphaE = dArr + (size_t)n * 2;              // e*2
  __half* xlh = (__half*)(alphaE + (size_t)e * 2);   // n*128 halves
  __half* bufHh = xlh + (size_t)n * 128;             // n*128 halves
  __half* Wt0 = bufHh + (size_t)n * 128;             // 128*128
  __half* Wt1 = Wt0 + 128 * 128;                     // 128*128
  __half* Wt2 = Wt1 + 128 * 128;                     // 64*128
  int2* csrPair = (int2*)(Wt2 + 64 * 128);           // e pairs
  int* row_ptr = (int*)(csrPair + e);                // n+1
  int* cursor = row_ptr + (n + 1);                   // n
  int* blockSums = cursor + n;                       // nb

  const int nb = (n + 255) / 256;
  const int ge = (e + 255) / 256;

  cvt_wt3_k<<<(128 * 128 + 255) / 256, 256, 0, stream>>>(W0, W1, W2, Wt0, Wt1, Wt2);
  cvt_f2h_k<<<((n * 32) + 255) / 256, 256, 0, stream>>>(x, bufHh, n * 32);

  hipMemsetAsync(cursor, 0, (size_t)n * sizeof(int), stream);
  count_dst_k<<<ge, 256, 0, stream>>>(dstIdx, cursor, e);
  block_sum_k<<<nb, 256, 0, stream>>>(cursor, blockSums, n);
  scan_sums_k<<<1, 256, 0, stream>>>(blockSums, nb, row_ptr + n);
  scan_apply_k<<<nb, 256, 0, stream>>>(cursor, blockSums, row_ptr, n);
  scatter_k<<<ge, 256, 0, stream>>>(srcIdx, dstIdx, cursor, csrPair, e);

  const int gb = (n + 63) / 64;
  const int gp1 = (n + 3) / 4;

  // layer 0
  gemm_attn_mfma_k<128, 2><<<gb, 256, 0, stream>>>(bufHh, Wt0, as0, ad0, xlh, sArr, dArr, n);
  alpha2_k<<<ge, 256, 0, stream>>>(sArr, dArr, csrPair, alphaE, e);
  edge2h_k<<<gp1, 256, 0, stream>>>(xlh, sArr, dArr, alphaE, b0, row_ptr, csrPair, bufHh, n);

  // layer 1
  gemm_attn_mfma_k<128, 2><<<gb, 256, 0, stream>>>(bufHh, Wt1, as1, ad1, xlh, sArr, dArr, n);
  alpha2_k<<<ge, 256, 0, stream>>>(sArr, dArr, csrPair, alphaE, e);
  edge2h_k<<<gp1, 256, 0, stream>>>(xlh, sArr, dArr, alphaE, b1, row_ptr, csrPair, bufHh, n);

  // layer 2 (H=1, no concat, no elu, fp32 out)
  gemm_attn_mfma_k<64, 1><<<gb, 256, 0, stream>>>(bufHh, Wt2, as2, ad2, xlh, sArr, dArr, n);
  alpha1_k<<<ge, 256, 0, stream>>>(sArr, dArr, csrPair, alphaE, e);
  edge1h_k<<<gp1, 256, 0, stream>>>(xlh, sArr, dArr, alphaE, b2, row_ptr, csrPair, out, n);
}

// Round 10
// 379.357 us; speedup vs baseline: 1.8428x; 1.0058x over previous
//
#include <hip/hip_runtime.h>
#include <hip/hip_fp16.h>
#include <math.h>

#define NEG_SLOPE 0.2f

__device__ __forceinline__ float lrelu(float v) { return v > 0.0f ? v : NEG_SLOPE * v; }

typedef _Float16 half8 __attribute__((ext_vector_type(8)));
typedef float floatx4 __attribute__((ext_vector_type(4)));

// ---------------- CSR build ----------------

__global__ void count_dst_k(const int* __restrict__ dst, int* __restrict__ counts, int e) {
  int i = blockIdx.x * 256 + threadIdx.x;
  if (i < e) atomicAdd(&counts[dst[i]], 1);
}

__global__ __launch_bounds__(256) void block_sum_k(const int* __restrict__ counts,
                                                   int* __restrict__ blockSums, int n) {
  int i = blockIdx.x * 256 + threadIdx.x;
  int v = (i < n) ? counts[i] : 0;
  for (int o = 32; o > 0; o >>= 1) v += __shfl_xor(v, o);
  __shared__ int ws[4];
  if ((threadIdx.x & 63) == 0) ws[threadIdx.x >> 6] = v;
  __syncthreads();
  if (threadIdx.x == 0) blockSums[blockIdx.x] = ws[0] + ws[1] + ws[2] + ws[3];
}

__global__ __launch_bounds__(256) void scan_sums_k(int* __restrict__ blockSums, int nb,
                                                   int* __restrict__ total_out) {
  __shared__ int sh[256];
  const int tid = threadIdx.x;
  int run = 0;
  for (int base = 0; base < nb; base += 256) {
    int i = base + tid;
    int v = (i < nb) ? blockSums[i] : 0;
    sh[tid] = v;
    __syncthreads();
    for (int o = 1; o < 256; o <<= 1) {
      int t = (tid >= o) ? sh[tid - o] : 0;
      __syncthreads();
      sh[tid] += t;
      __syncthreads();
    }
    int chunkTotal = sh[255];
    if (i < nb) blockSums[i] = run + sh[tid] - v;
    __syncthreads();
    run += chunkTotal;
  }
  if (tid == 0) *total_out = run;
}

__global__ __launch_bounds__(256) void scan_apply_k(int* __restrict__ counts_cursor,
                                                    const int* __restrict__ blockOffs,
                                                    int* __restrict__ row_ptr, int n) {
  __shared__ int sh[256];
  const int tid = threadIdx.x;
  const int i = blockIdx.x * 256 + tid;
  int v = (i < n) ? counts_cursor[i] : 0;
  sh[tid] = v;
  __syncthreads();
  for (int o = 1; o < 256; o <<= 1) {
    int t = (tid >= o) ? sh[tid - o] : 0;
    __syncthreads();
    sh[tid] += t;
    __syncthreads();
  }
  if (i < n) {
    int excl = blockOffs[blockIdx.x] + sh[tid] - v;
    row_ptr[i] = excl;
    counts_cursor[i] = excl;
  }
}

// XCD-windowed scatter: nodes split into 8 windows; block b serves window b&7
// (consecutive blocks round-robin across the 8 XCDs, so one window's writes --
// hence each csr cache line -- come from one XCD and merge in its L2).
// Payload is src only (4B). Perf heuristic only: windows are disjoint, so
// correctness never depends on the XCD mapping.
__global__ __launch_bounds__(256) void scatter_win_k(const int* __restrict__ src,
                                                     const int* __restrict__ dst,
                                                     int* __restrict__ cursor,
                                                     int* __restrict__ csr,
                                                     int e, int winSize) {
  const int win = blockIdx.x & 7;
  const int lo = win * winSize;
  const int hi = lo + winSize;
  const int base = (blockIdx.x >> 3) * 4096 + threadIdx.x;
  for (int t = 0; t < 16; ++t) {
    int i = base + t * 256;
    if (i < e) {
      int d = dst[i];
      if (d >= lo && d < hi) {
        int pos = atomicAdd(&cursor[d], 1);
        csr[pos] = src[i];
      }
    }
  }
}

// ---------------- dtype converts (once per launch) ----------------

__global__ __launch_bounds__(256) void cvt_f2h_k(const float* __restrict__ src,
                                                 __half* __restrict__ dst, int count4) {
  int i = blockIdx.x * 256 + threadIdx.x;
  if (i < count4) {
    float4 v = ((const float4*)src)[i];
    __half2 a = __floats2half2_rn(v.x, v.y);
    __half2 b = __floats2half2_rn(v.z, v.w);
    uint2 pk;
    pk.x = *(unsigned int*)&a;
    pk.y = *(unsigned int*)&b;
    ((uint2*)dst)[i] = pk;
  }
}

__global__ __launch_bounds__(256) void cvt_wt3_k(const float* __restrict__ W0,
                                                 const float* __restrict__ W1,
                                                 const float* __restrict__ W2,
                                                 __half* __restrict__ Wt0,
                                                 __half* __restrict__ Wt1,
                                                 __half* __restrict__ Wt2) {
  int i = blockIdx.x * 256 + threadIdx.x;
  if (i < 128 * 128) {
    int col = i >> 7, k = i & 127;
    Wt0[i] = __float2half(W0[k * 128 + col]);
    Wt1[i] = __float2half(W1[k * 128 + col]);
    if (col < 64) Wt2[(size_t)col * 128 + k] = __float2half(W2[k * 64 + col]);
  }
}

// ---------------- MFMA GEMM + fused attention dots ----------------

template<int M, int H_>
__global__ __launch_bounds__(256) void gemm_attn_mfma_k(const __half* __restrict__ Xh,
                                                        const __half* __restrict__ Wt,
                                                        const float* __restrict__ a_src,
                                                        const float* __restrict__ a_dst,
                                                        __half* __restrict__ Yh,
                                                        float* __restrict__ sArr,
                                                        float* __restrict__ dArr, int n) {
  constexpr int CT = M / 16;
  constexpr int LP = 136;  // LDS row pitch in halves (272B: 2-way conflict = free)
  __shared__ _Float16 Xs[64 * LP];
  __shared__ _Float16 Ws[M * LP];
  const int tid = threadIdx.x;
  const int w = tid >> 6;
  const int lane = tid & 63;
  const int l15 = lane & 15;
  const int quad = lane >> 4;
  const int rb = blockIdx.x * 64;

  for (int t = 0; t < 4; ++t) {
    int idx = tid + t * 256;
    int r = idx >> 4, c8 = idx & 15;
    uint4 v = make_uint4(0, 0, 0, 0);
    if (rb + r < n) v = *(const uint4*)(Xh + (size_t)(rb + r) * 128 + c8 * 8);
    *(uint4*)&Xs[r * LP + c8 * 8] = v;
  }
  for (int t = 0; t < CT; ++t) {
    int idx = tid + t * 256;
    int r = idx >> 4, c8 = idx & 15;
    *(uint4*)&Ws[r * LP + c8 * 8] = *(const uint4*)(Wt + (size_t)r * 128 + c8 * 8);
  }
  __syncthreads();

  floatx4 acc[CT];
  for (int c = 0; c < CT; ++c)
    for (int j = 0; j < 4; ++j) acc[c][j] = 0.f;

  const int arow = w * 16 + l15;
  for (int kq = 0; kq < 4; ++kq) {
    half8 a = *(const half8*)&Xs[arow * LP + kq * 32 + quad * 8];
    for (int c = 0; c < CT; ++c) {
      half8 b = *(const half8*)&Ws[(c * 16 + l15) * LP + kq * 32 + quad * 8];
      acc[c] = __builtin_amdgcn_mfma_f32_16x16x32_f16(a, b, acc[c], 0, 0, 0);
    }
  }

  float as[CT], ad[CT];
  for (int c = 0; c < CT; ++c) {
    as[c] = a_src[c * 16 + l15];
    ad[c] = a_dst[c * 16 + l15];
  }

  for (int c = 0; c < CT; ++c) {
    for (int r = 0; r < 4; ++r) {
      int row = rb + w * 16 + quad * 4 + r;
      if (row < n) Yh[(size_t)row * M + c * 16 + l15] = __float2half(acc[c][r]);
    }
  }

  for (int r = 0; r < 4; ++r) {
    int row = rb + w * 16 + quad * 4 + r;
    float s0 = 0.f, d0 = 0.f, s1 = 0.f, d1 = 0.f;
    if (H_ == 2) {
      for (int c = 0; c < CT / 2; ++c) {
        s0 += acc[c][r] * as[c];
        d0 += acc[c][r] * ad[c];
      }
      for (int c = CT / 2; c < CT; ++c) {
        s1 += acc[c][r] * as[c];
        d1 += acc[c][r] * ad[c];
      }
    } else {
      for (int c = 0; c < CT; ++c) {
        s0 += acc[c][r] * as[c];
        d0 += acc[c][r] * ad[c];
      }
    }
    for (int o = 1; o < 16; o <<= 1) {
      s0 += __shfl_xor(s0, o);
      d0 += __shfl_xor(d0, o);
      if (H_ == 2) {
        s1 += __shfl_xor(s1, o);
        d1 += __shfl_xor(d1, o);
      }
    }
    if (l15 == 0 && row < n) {
      if (H_ == 2) {
        sArr[row * 2] = s0;
        sArr[row * 2 + 1] = s1;
        dArr[row * 2] = d0;
        dArr[row * 2 + 1] = d1;
      } else {
        sArr[row] = s0;
        dArr[row] = d0;
      }
    }
  }
}

// ---------------- aggregation: one wave per node, fp16 gather, weights in-kernel ----
// Per-edge weight exp(lrelu(s[src]+dn)) computed from a broadcast sArr[src] load
// (src is wave-uniform); dn = dArr[node] is loop-invariant. Softmax denominator
// accumulated alongside (linear until the final divide).

__global__ __launch_bounds__(256) void edge2h_k(const __half* __restrict__ xlh,
                                                const float* __restrict__ sArr,
                                                const float* __restrict__ dArr,
                                                const float* __restrict__ bias,
                                                const int* __restrict__ row_ptr,
                                                const int* __restrict__ csr,
                                                __half* __restrict__ outh, int n) {
  const int node = blockIdx.x * 4 + (threadIdx.x >> 6);
  const int lane = threadIdx.x & 63;
  if (node >= n) return;
  const int row = row_ptr[node];
  const int deg = row_ptr[node + 1] - row;
  const unsigned int* __restrict__ xlu = (const unsigned int*)xlh;
  const float2* __restrict__ s2 = (const float2*)sArr;
  const float2 dn = ((const float2*)dArr)[node];
  const bool lo = lane < 32;
  float ax = 0.f, ay = 0.f;
  float den0 = 0.f, den1 = 0.f;
  int j = 0;
  for (; j + 8 <= deg; j += 8) {
    int idx[8];
    float2 sv[8];
    unsigned int p[8];
    for (int t = 0; t < 8; ++t) idx[t] = csr[row + j + t];
    for (int t = 0; t < 8; ++t) sv[t] = s2[idx[t]];
    for (int t = 0; t < 8; ++t) p[t] = xlu[(size_t)idx[t] * 64 + lane];
    for (int t = 0; t < 8; ++t) {
      float w0 = __expf(lrelu(sv[t].x + dn.x));
      float w1 = __expf(lrelu(sv[t].y + dn.y));
      den0 += w0;
      den1 += w1;
      float2 v = __half22float2(*(__half2*)&p[t]);
      float u = lo ? w0 : w1;
      ax += u * v.x;
      ay += u * v.y;
    }
  }
  for (; j < deg; ++j) {
    int i0 = csr[row + j];
    float2 sv = s2[i0];
    unsigned int p = xlu[(size_t)i0 * 64 + lane];
    float w0 = __expf(lrelu(sv.x + dn.x));
    float w1 = __expf(lrelu(sv.y + dn.y));
    den0 += w0;
    den1 += w1;
    float2 v = __half22float2(*(__half2*)&p);
    float u = lo ? w0 : w1;
    ax += u * v.x;
    ay += u * v.y;
  }
  // self loop
  const float2 sn = s2[node];
  float wS0 = __expf(lrelu(sn.x + dn.x)), wS1 = __expf(lrelu(sn.y + dn.y));
  den0 += wS0;
  den1 += wS1;
  unsigned int pS = xlu[(size_t)node * 64 + lane];
  float2 vS = __half22float2(*(__half2*)&pS);
  float uS = lo ? wS0 : wS1;
  ax += uS * vS.x;
  ay += uS * vS.y;

  float wi = 1.f / (lo ? den0 : den1);
  float2 bb = ((const float2*)bias)[lane];
  float rx = ax * wi + bb.x;
  float ry = ay * wi + bb.y;
  rx = rx > 0.f ? rx : expm1f(rx);
  ry = ry > 0.f ? ry : expm1f(ry);
  __half2 o = __floats2half2_rn(rx, ry);
  ((__half2*)outh)[(size_t)node * 64 + lane] = o;
}

__global__ __launch_bounds__(256) void edge1h_k(const __half* __restrict__ xlh,
                                                const float* __restrict__ sArr,
                                                const float* __restrict__ dArr,
                                                const float* __restrict__ bias,
                                                const int* __restrict__ row_ptr,
                                                const int* __restrict__ csr,
                                                float* __restrict__ outp, int n) {
  const int node = blockIdx.x * 4 + (threadIdx.x >> 6);
  const int lane = threadIdx.x & 63;
  if (node >= n) return;
  const int row = row_ptr[node];
  const int deg = row_ptr[node + 1] - row;
  const float dn = dArr[node];
  float ax = 0.f;
  float den = 0.f;
  int j = 0;
  for (; j + 8 <= deg; j += 8) {
    int idx[8];
    float sv[8];
    __half v[8];
    for (int t = 0; t < 8; ++t) idx[t] = csr[row + j + t];
    for (int t = 0; t < 8; ++t) sv[t] = sArr[idx[t]];
    for (int t = 0; t < 8; ++t) v[t] = xlh[(size_t)idx[t] * 64 + lane];
    for (int t = 0; t < 8; ++t) {
      float a = __expf(lrelu(sv[t] + dn));
      den += a;
      ax += a * __half2float(v[t]);
    }
  }
  for (; j < deg; ++j) {
    int i0 = csr[row + j];
    float a = __expf(lrelu(sArr[i0] + dn));
    den += a;
    ax += a * __half2float(xlh[(size_t)i0 * 64 + lane]);
  }
  float wS = __expf(lrelu(sArr[node] + dn));
  den += wS;
  ax += wS * __half2float(xlh[(size_t)node * 64 + lane]);

  float r = ax / den + bias[lane];
  outp[(size_t)node * 64 + lane] = r;
}

// ---------------- launch ----------------

extern "C" void kernel_launch(void* const* d_in, const int* in_sizes, int n_in,
                              void* d_out, int out_size, void* d_ws, size_t ws_size,
                              hipStream_t stream) {
  const float* x  = (const float*)d_in[0];
  const int* ei   = (const int*)d_in[1];
  const float* W0 = (const float*)d_in[2];
  const float* as0 = (const float*)d_in[3];
  const float* ad0 = (const float*)d_in[4];
  const float* b0 = (const float*)d_in[5];
  const float* W1 = (const float*)d_in[6];
  const float* as1 = (const float*)d_in[7];
  const float* ad1 = (const float*)d_in[8];
  const float* b1 = (const float*)d_in[9];
  const float* W2 = (const float*)d_in[10];
  const float* as2 = (const float*)d_in[11];
  const float* ad2 = (const float*)d_in[12];
  const float* b2 = (const float*)d_in[13];
  float* out = (float*)d_out;

  const int n = in_sizes[0] / 128;
  const int e = in_sizes[1] / 2;
  const int* srcIdx = ei;
  const int* dstIdx = ei + e;

  float* ws = (float*)d_ws;
  float* sArr = ws;                                  // n*2
  float* dArr = sArr + (size_t)n * 2;                // n*2
  __half* xlh = (__half*)(dArr + (size_t)n * 2);     // n*128 halves
  __half* bufHh = xlh + (size_t)n * 128;             // n*128 halves
  __half* Wt0 = bufHh + (size_t)n * 128;             // 128*128
  __half* Wt1 = Wt0 + 128 * 128;                     // 128*128
  __half* Wt2 = Wt1 + 128 * 128;                     // 64*128
  int* csr = (int*)(Wt2 + 64 * 128);                 // e
  int* row_ptr = csr + e;                            // n+1
  int* cursor = row_ptr + (n + 1);                   // n
  int* blockSums = cursor + n;                       // nb

  const int nb = (n + 255) / 256;
  const int ge = (e + 255) / 256;
  const int winSize = (n + 7) / 8;
  const int gscat = 8 * ((e + 4095) / 4096);

  cvt_wt3_k<<<(128 * 128 + 255) / 256, 256, 0, stream>>>(W0, W1, W2, Wt0, Wt1, Wt2);
  cvt_f2h_k<<<((n * 32) + 255) / 256, 256, 0, stream>>>(x, bufHh, n * 32);

  hipMemsetAsync(cursor, 0, (size_t)n * sizeof(int), stream);
  count_dst_k<<<ge, 256, 0, stream>>>(dstIdx, cursor, e);
  block_sum_k<<<nb, 256, 0, stream>>>(cursor, blockSums, n);
  scan_sums_k<<<1, 256, 0, stream>>>(blockSums, nb, row_ptr + n);
  scan_apply_k<<<nb, 256, 0, stream>>>(cursor, blockSums, row_ptr, n);
  scatter_win_k<<<gscat, 256, 0, stream>>>(srcIdx, dstIdx, cursor, csr, e, winSize);

  const int gb = (n + 63) / 64;
  const int gp1 = (n + 3) / 4;

  // layer 0
  gemm_attn_mfma_k<128, 2><<<gb, 256, 0, stream>>>(bufHh, Wt0, as0, ad0, xlh, sArr, dArr, n);
  edge2h_k<<<gp1, 256, 0, stream>>>(xlh, sArr, dArr, b0, row_ptr, csr, bufHh, n);

  // layer 1
  gemm_attn_mfma_k<128, 2><<<gb, 256, 0, stream>>>(bufHh, Wt1, as1, ad1, xlh, sArr, dArr, n);
  edge2h_k<<<gp1, 256, 0, stream>>>(xlh, sArr, dArr, b1, row_ptr, csr, bufHh, n);

  // layer 2 (H=1, no concat, no elu, fp32 out)
  gemm_attn_mfma_k<64, 1><<<gb, 256, 0, stream>>>(bufHh, Wt2, as2, ad2, xlh, sArr, dArr, n);
  edge1h_k<<<gp1, 256, 0, stream>>>(xlh, sArr, dArr, b2, row_ptr, csr, out, n);
}

// Round 11
// 378.468 us; speedup vs baseline: 1.8471x; 1.0023x over previous
//
#include <hip/hip_runtime.h>
#include <hip/hip_fp16.h>
#include <math.h>

#define NEG_SLOPE 0.2f

__device__ __forceinline__ float lrelu(float v) { return v > 0.0f ? v : NEG_SLOPE * v; }

typedef _Float16 half8 __attribute__((ext_vector_type(8)));
typedef float floatx4 __attribute__((ext_vector_type(4)));

// ---------------- CSR build ----------------

__global__ void count_dst_k(const int* __restrict__ dst, int* __restrict__ counts, int e) {
  int i = blockIdx.x * 256 + threadIdx.x;
  if (i < e) atomicAdd(&counts[dst[i]], 1);
}

__global__ __launch_bounds__(256) void block_sum_k(const int* __restrict__ counts,
                                                   int* __restrict__ blockSums, int n) {
  int i = blockIdx.x * 256 + threadIdx.x;
  int v = (i < n) ? counts[i] : 0;
  for (int o = 32; o > 0; o >>= 1) v += __shfl_xor(v, o);
  __shared__ int ws[4];
  if ((threadIdx.x & 63) == 0) ws[threadIdx.x >> 6] = v;
  __syncthreads();
  if (threadIdx.x == 0) blockSums[blockIdx.x] = ws[0] + ws[1] + ws[2] + ws[3];
}

__global__ __launch_bounds__(256) void scan_sums_k(int* __restrict__ blockSums, int nb,
                                                   int* __restrict__ total_out) {
  __shared__ int sh[256];
  const int tid = threadIdx.x;
  int run = 0;
  for (int base = 0; base < nb; base += 256) {
    int i = base + tid;
    int v = (i < nb) ? blockSums[i] : 0;
    sh[tid] = v;
    __syncthreads();
    for (int o = 1; o < 256; o <<= 1) {
      int t = (tid >= o) ? sh[tid - o] : 0;
      __syncthreads();
      sh[tid] += t;
      __syncthreads();
    }
    int chunkTotal = sh[255];
    if (i < nb) blockSums[i] = run + sh[tid] - v;
    __syncthreads();
    run += chunkTotal;
  }
  if (tid == 0) *total_out = run;
}

__global__ __launch_bounds__(256) void scan_apply_k(int* __restrict__ counts_cursor,
                                                    const int* __restrict__ blockOffs,
                                                    int* __restrict__ row_ptr, int n) {
  __shared__ int sh[256];
  const int tid = threadIdx.x;
  const int i = blockIdx.x * 256 + tid;
  int v = (i < n) ? counts_cursor[i] : 0;
  sh[tid] = v;
  __syncthreads();
  for (int o = 1; o < 256; o <<= 1) {
    int t = (tid >= o) ? sh[tid - o] : 0;
    __syncthreads();
    sh[tid] += t;
    __syncthreads();
  }
  if (i < n) {
    int excl = blockOffs[blockIdx.x] + sh[tid] - v;
    row_ptr[i] = excl;
    counts_cursor[i] = excl;
  }
}

// XCD-windowed scatter (perf heuristic; windows disjoint so correctness is
// independent of workgroup->XCD mapping).
__global__ __launch_bounds__(256) void scatter_win_k(const int* __restrict__ src,
                                                     const int* __restrict__ dst,
                                                     int* __restrict__ cursor,
                                                     int* __restrict__ csr,
                                                     int e, int winSize) {
  const int win = blockIdx.x & 7;
  const int lo = win * winSize;
  const int hi = lo + winSize;
  const int base = (blockIdx.x >> 3) * 4096 + threadIdx.x;
  for (int t = 0; t < 16; ++t) {
    int i = base + t * 256;
    if (i < e) {
      int d = dst[i];
      if (d >= lo && d < hi) {
        int pos = atomicAdd(&cursor[d], 1);
        csr[pos] = src[i];
      }
    }
  }
}

// ---------------- dtype converts (once per launch) ----------------

__global__ __launch_bounds__(256) void cvt_f2h_k(const float* __restrict__ src,
                                                 __half* __restrict__ dst, int count4) {
  int i = blockIdx.x * 256 + threadIdx.x;
  if (i < count4) {
    float4 v = ((const float4*)src)[i];
    __half2 a = __floats2half2_rn(v.x, v.y);
    __half2 b = __floats2half2_rn(v.z, v.w);
    uint2 pk;
    pk.x = *(unsigned int*)&a;
    pk.y = *(unsigned int*)&b;
    ((uint2*)dst)[i] = pk;
  }
}

__global__ __launch_bounds__(256) void cvt_wt3_k(const float* __restrict__ W0,
                                                 const float* __restrict__ W1,
                                                 const float* __restrict__ W2,
                                                 __half* __restrict__ Wt0,
                                                 __half* __restrict__ Wt1,
                                                 __half* __restrict__ Wt2) {
  int i = blockIdx.x * 256 + threadIdx.x;
  if (i < 128 * 128) {
    int col = i >> 7, k = i & 127;
    Wt0[i] = __float2half(W0[k * 128 + col]);
    Wt1[i] = __float2half(W1[k * 128 + col]);
    if (col < 64) Wt2[(size_t)col * 128 + k] = __float2half(W2[k * 64 + col]);
  }
}

// ---------------- MFMA GEMM + fused attention dots ----------------

template<int M, int H_>
__global__ __launch_bounds__(256) void gemm_attn_mfma_k(const __half* __restrict__ Xh,
                                                        const __half* __restrict__ Wt,
                                                        const float* __restrict__ a_src,
                                                        const float* __restrict__ a_dst,
                                                        __half* __restrict__ Yh,
                                                        float* __restrict__ sArr,
                                                        float* __restrict__ dArr, int n) {
  constexpr int CT = M / 16;
  constexpr int LP = 136;  // LDS row pitch in halves (272B: 2-way conflict = free)
  __shared__ _Float16 Xs[64 * LP];
  __shared__ _Float16 Ws[M * LP];
  const int tid = threadIdx.x;
  const int w = tid >> 6;
  const int lane = tid & 63;
  const int l15 = lane & 15;
  const int quad = lane >> 4;
  const int rb = blockIdx.x * 64;

  for (int t = 0; t < 4; ++t) {
    int idx = tid + t * 256;
    int r = idx >> 4, c8 = idx & 15;
    uint4 v = make_uint4(0, 0, 0, 0);
    if (rb + r < n) v = *(const uint4*)(Xh + (size_t)(rb + r) * 128 + c8 * 8);
    *(uint4*)&Xs[r * LP + c8 * 8] = v;
  }
  for (int t = 0; t < CT; ++t) {
    int idx = tid + t * 256;
    int r = idx >> 4, c8 = idx & 15;
    *(uint4*)&Ws[r * LP + c8 * 8] = *(const uint4*)(Wt + (size_t)r * 128 + c8 * 8);
  }
  __syncthreads();

  floatx4 acc[CT];
  for (int c = 0; c < CT; ++c)
    for (int j = 0; j < 4; ++j) acc[c][j] = 0.f;

  const int arow = w * 16 + l15;
  for (int kq = 0; kq < 4; ++kq) {
    half8 a = *(const half8*)&Xs[arow * LP + kq * 32 + quad * 8];
    for (int c = 0; c < CT; ++c) {
      half8 b = *(const half8*)&Ws[(c * 16 + l15) * LP + kq * 32 + quad * 8];
      acc[c] = __builtin_amdgcn_mfma_f32_16x16x32_f16(a, b, acc[c], 0, 0, 0);
    }
  }

  float as[CT], ad[CT];
  for (int c = 0; c < CT; ++c) {
    as[c] = a_src[c * 16 + l15];
    ad[c] = a_dst[c * 16 + l15];
  }

  for (int c = 0; c < CT; ++c) {
    for (int r = 0; r < 4; ++r) {
      int row = rb + w * 16 + quad * 4 + r;
      if (row < n) Yh[(size_t)row * M + c * 16 + l15] = __float2half(acc[c][r]);
    }
  }

  for (int r = 0; r < 4; ++r) {
    int row = rb + w * 16 + quad * 4 + r;
    float s0 = 0.f, d0 = 0.f, s1 = 0.f, d1 = 0.f;
    if (H_ == 2) {
      for (int c = 0; c < CT / 2; ++c) {
        s0 += acc[c][r] * as[c];
        d0 += acc[c][r] * ad[c];
      }
      for (int c = CT / 2; c < CT; ++c) {
        s1 += acc[c][r] * as[c];
        d1 += acc[c][r] * ad[c];
      }
    } else {
      for (int c = 0; c < CT; ++c) {
        s0 += acc[c][r] * as[c];
        d0 += acc[c][r] * ad[c];
      }
    }
    for (int o = 1; o < 16; o <<= 1) {
      s0 += __shfl_xor(s0, o);
      d0 += __shfl_xor(d0, o);
      if (H_ == 2) {
        s1 += __shfl_xor(s1, o);
        d1 += __shfl_xor(d1, o);
      }
    }
    if (l15 == 0 && row < n) {
      if (H_ == 2) {
        sArr[row * 2] = s0;
        sArr[row * 2 + 1] = s1;
        dArr[row * 2] = d0;
        dArr[row * 2 + 1] = d1;
      } else {
        sArr[row] = s0;
        dArr[row] = d0;
      }
    }
  }
}

// ---------------- aggregation: one wave per node, fp16 gather ----------------
// ONE exp per lane per edge: each lane computes only its own head's weight
// (selected s + selected dn); since every lane's loop spans all edges, the
// per-lane accumulator of its own head's weights IS that head's denominator.

__global__ __launch_bounds__(256) void edge2h_k(const __half* __restrict__ xlh,
                                                const float* __restrict__ sArr,
                                                const float* __restrict__ dArr,
                                                const float* __restrict__ bias,
                                                const int* __restrict__ row_ptr,
                                                const int* __restrict__ csr,
                                                __half* __restrict__ outh, int n) {
  const int node = blockIdx.x * 4 + (threadIdx.x >> 6);
  const int lane = threadIdx.x & 63;
  if (node >= n) return;
  const int row = row_ptr[node];
  const int deg = row_ptr[node + 1] - row;
  const unsigned int* __restrict__ xlu = (const unsigned int*)xlh;
  const float2* __restrict__ s2 = (const float2*)sArr;
  const float2 dn = ((const float2*)dArr)[node];
  const bool lo = lane < 32;
  const float dnsel = lo ? dn.x : dn.y;
  float ax = 0.f, ay = 0.f;
  float den = 0.f;
  int j = 0;
  for (; j + 8 <= deg; j += 8) {
    int idx[8];
    float2 sv[8];
    unsigned int p[8];
    for (int t = 0; t < 8; ++t) idx[t] = csr[row + j + t];
    for (int t = 0; t < 8; ++t) sv[t] = s2[idx[t]];
    for (int t = 0; t < 8; ++t) p[t] = xlu[(size_t)idx[t] * 64 + lane];
    for (int t = 0; t < 8; ++t) {
      float w = __expf(lrelu((lo ? sv[t].x : sv[t].y) + dnsel));
      den += w;
      float2 v = __half22float2(*(__half2*)&p[t]);
      ax += w * v.x;
      ay += w * v.y;
    }
  }
  for (; j < deg; ++j) {
    int i0 = csr[row + j];
    float2 sv = s2[i0];
    unsigned int p = xlu[(size_t)i0 * 64 + lane];
    float w = __expf(lrelu((lo ? sv.x : sv.y) + dnsel));
    den += w;
    float2 v = __half22float2(*(__half2*)&p);
    ax += w * v.x;
    ay += w * v.y;
  }
  // self loop
  const float2 sn = s2[node];
  float wS = __expf(lrelu((lo ? sn.x : sn.y) + dnsel));
  den += wS;
  unsigned int pS = xlu[(size_t)node * 64 + lane];
  float2 vS = __half22float2(*(__half2*)&pS);
  ax += wS * vS.x;
  ay += wS * vS.y;

  float wi = 1.f / den;
  float2 bb = ((const float2*)bias)[lane];
  float rx = ax * wi + bb.x;
  float ry = ay * wi + bb.y;
  rx = rx > 0.f ? rx : expm1f(rx);
  ry = ry > 0.f ? ry : expm1f(ry);
  __half2 o = __floats2half2_rn(rx, ry);
  ((__half2*)outh)[(size_t)node * 64 + lane] = o;
}

__global__ __launch_bounds__(256) void edge1h_k(const __half* __restrict__ xlh,
                                                const float* __restrict__ sArr,
                                                const float* __restrict__ dArr,
                                                const float* __restrict__ bias,
                                                const int* __restrict__ row_ptr,
                                                const int* __restrict__ csr,
                                                float* __restrict__ outp, int n) {
  const int node = blockIdx.x * 4 + (threadIdx.x >> 6);
  const int lane = threadIdx.x & 63;
  if (node >= n) return;
  const int row = row_ptr[node];
  const int deg = row_ptr[node + 1] - row;
  const float dn = dArr[node];
  float ax = 0.f;
  float den = 0.f;
  int j = 0;
  for (; j + 8 <= deg; j += 8) {
    int idx[8];
    float sv[8];
    __half v[8];
    for (int t = 0; t < 8; ++t) idx[t] = csr[row + j + t];
    for (int t = 0; t < 8; ++t) sv[t] = sArr[idx[t]];
    for (int t = 0; t < 8; ++t) v[t] = xlh[(size_t)idx[t] * 64 + lane];
    for (int t = 0; t < 8; ++t) {
      float a = __expf(lrelu(sv[t] + dn));
      den += a;
      ax += a * __half2float(v[t]);
    }
  }
  for (; j < deg; ++j) {
    int i0 = csr[row + j];
    float a = __expf(lrelu(sArr[i0] + dn));
    den += a;
    ax += a * __half2float(xlh[(size_t)i0 * 64 + lane]);
  }
  float wS = __expf(lrelu(sArr[node] + dn));
  den += wS;
  ax += wS * __half2float(xlh[(size_t)node * 64 + lane]);

  float r = ax / den + bias[lane];
  outp[(size_t)node * 64 + lane] = r;
}

// ---------------- launch ----------------

extern "C" void kernel_launch(void* const* d_in, const int* in_sizes, int n_in,
                              void* d_out, int out_size, void* d_ws, size_t ws_size,
                              hipStream_t stream) {
  const float* x  = (const float*)d_in[0];
  const int* ei   = (const int*)d_in[1];
  const float* W0 = (const float*)d_in[2];
  const float* as0 = (const float*)d_in[3];
  const float* ad0 = (const float*)d_in[4];
  const float* b0 = (const float*)d_in[5];
  const float* W1 = (const float*)d_in[6];
  const float* as1 = (const float*)d_in[7];
  const float* ad1 = (const float*)d_in[8];
  const float* b1 = (const float*)d_in[9];
  const float* W2 = (const float*)d_in[10];
  const float* as2 = (const float*)d_in[11];
  const float* ad2 = (const float*)d_in[12];
  const float* b2 = (const float*)d_in[13];
  float* out = (float*)d_out;

  const int n = in_sizes[0] / 128;
  const int e = in_sizes[1] / 2;
  const int* srcIdx = ei;
  const int* dstIdx = ei + e;

  float* ws = (float*)d_ws;
  float* sArr = ws;                                  // n*2
  float* dArr = sArr + (size_t)n * 2;                // n*2
  __half* xlh = (__half*)(dArr + (size_t)n * 2);     // n*128 halves
  __half* bufHh = xlh + (size_t)n * 128;             // n*128 halves
  __half* Wt0 = bufHh + (size_t)n * 128;             // 128*128
  __half* Wt1 = Wt0 + 128 * 128;                     // 128*128
  __half* Wt2 = Wt1 + 128 * 128;                     // 64*128
  int* csr = (int*)(Wt2 + 64 * 128);                 // e
  int* row_ptr = csr + e;                            // n+1
  int* cursor = row_ptr + (n + 1);                   // n
  int* blockSums = cursor + n;                       // nb

  const int nb = (n + 255) / 256;
  const int ge = (e + 255) / 256;
  const int winSize = (n + 7) / 8;
  const int gscat = 8 * ((e + 4095) / 4096);

  cvt_wt3_k<<<(128 * 128 + 255) / 256, 256, 0, stream>>>(W0, W1, W2, Wt0, Wt1, Wt2);
  cvt_f2h_k<<<((n * 32) + 255) / 256, 256, 0, stream>>>(x, bufHh, n * 32);

  hipMemsetAsync(cursor, 0, (size_t)n * sizeof(int), stream);
  count_dst_k<<<ge, 256, 0, stream>>>(dstIdx, cursor, e);
  block_sum_k<<<nb, 256, 0, stream>>>(cursor, blockSums, n);
  scan_sums_k<<<1, 256, 0, stream>>>(blockSums, nb, row_ptr + n);
  scan_apply_k<<<nb, 256, 0, stream>>>(cursor, blockSums, row_ptr, n);
  scatter_win_k<<<gscat, 256, 0, stream>>>(srcIdx, dstIdx, cursor, csr, e, winSize);

  const int gb = (n + 63) / 64;
  const int gp1 = (n + 3) / 4;

  // layer 0
  gemm_attn_mfma_k<128, 2><<<gb, 256, 0, stream>>>(bufHh, Wt0, as0, ad0, xlh, sArr, dArr, n);
  edge2h_k<<<gp1, 256, 0, stream>>>(xlh, sArr, dArr, b0, row_ptr, csr, bufHh, n);

  // layer 1
  gemm_attn_mfma_k<128, 2><<<gb, 256, 0, stream>>>(bufHh, Wt1, as1, ad1, xlh, sArr, dArr, n);
  edge2h_k<<<gp1, 256, 0, stream>>>(xlh, sArr, dArr, b1, row_ptr, csr, bufHh, n);

  // layer 2 (H=1, no concat, no elu, fp32 out)
  gemm_attn_mfma_k<64, 1><<<gb, 256, 0, stream>>>(bufHh, Wt2, as2, ad2, xlh, sArr, dArr, n);
  edge1h_k<<<gp1, 256, 0, stream>>>(xlh, sArr, dArr, b2, row_ptr, csr, out, n);
}

// Round 12
// 324.077 us; speedup vs baseline: 2.1571x; 1.1678x over previous
//
#include <hip/hip_runtime.h>
#include <hip/hip_fp16.h>
#include <math.h>

#define NEG_SLOPE 0.2f

__device__ __forceinline__ float lrelu(float v) { return v > 0.0f ? v : NEG_SLOPE * v; }

typedef _Float16 half8 __attribute__((ext_vector_type(8)));
typedef float floatx4 __attribute__((ext_vector_type(4)));

// ---------------- CSR build ----------------

// XCD-windowed count (same trick as scatter: one window's atomics come from one
// XCD, merging in its L2; windows disjoint so correctness is mapping-independent).
__global__ __launch_bounds__(256) void count_win_k(const int* __restrict__ dst,
                                                   int* __restrict__ counts,
                                                   int e, int winSize) {
  const int win = blockIdx.x & 7;
  const int lo = win * winSize;
  const int hi = lo + winSize;
  const int base = (blockIdx.x >> 3) * 4096 + threadIdx.x;
  for (int t = 0; t < 16; ++t) {
    int i = base + t * 256;
    if (i < e) {
      int d = dst[i];
      if (d >= lo && d < hi) atomicAdd(&counts[d], 1);
    }
  }
}

__global__ __launch_bounds__(256) void block_sum_k(const int* __restrict__ counts,
                                                   int* __restrict__ blockSums, int n) {
  int i = blockIdx.x * 256 + threadIdx.x;
  int v = (i < n) ? counts[i] : 0;
  for (int o = 32; o > 0; o >>= 1) v += __shfl_xor(v, o);
  __shared__ int ws[4];
  if ((threadIdx.x & 63) == 0) ws[threadIdx.x >> 6] = v;
  __syncthreads();
  if (threadIdx.x == 0) blockSums[blockIdx.x] = ws[0] + ws[1] + ws[2] + ws[3];
}

__global__ __launch_bounds__(256) void scan_sums_k(int* __restrict__ blockSums, int nb,
                                                   int* __restrict__ total_out) {
  __shared__ int sh[256];
  const int tid = threadIdx.x;
  int run = 0;
  for (int base = 0; base < nb; base += 256) {
    int i = base + tid;
    int v = (i < nb) ? blockSums[i] : 0;
    sh[tid] = v;
    __syncthreads();
    for (int o = 1; o < 256; o <<= 1) {
      int t = (tid >= o) ? sh[tid - o] : 0;
      __syncthreads();
      sh[tid] += t;
      __syncthreads();
    }
    int chunkTotal = sh[255];
    if (i < nb) blockSums[i] = run + sh[tid] - v;
    __syncthreads();
    run += chunkTotal;
  }
  if (tid == 0) *total_out = run;
}

__global__ __launch_bounds__(256) void scan_apply_k(int* __restrict__ counts_cursor,
                                                    const int* __restrict__ blockOffs,
                                                    int* __restrict__ row_ptr, int n) {
  __shared__ int sh[256];
  const int tid = threadIdx.x;
  const int i = blockIdx.x * 256 + tid;
  int v = (i < n) ? counts_cursor[i] : 0;
  sh[tid] = v;
  __syncthreads();
  for (int o = 1; o < 256; o <<= 1) {
    int t = (tid >= o) ? sh[tid - o] : 0;
    __syncthreads();
    sh[tid] += t;
    __syncthreads();
  }
  if (i < n) {
    int excl = blockOffs[blockIdx.x] + sh[tid] - v;
    row_ptr[i] = excl;
    counts_cursor[i] = excl;
  }
}

__global__ __launch_bounds__(256) void scatter_win_k(const int* __restrict__ src,
                                                     const int* __restrict__ dst,
                                                     int* __restrict__ cursor,
                                                     int* __restrict__ csr,
                                                     int e, int winSize) {
  const int win = blockIdx.x & 7;
  const int lo = win * winSize;
  const int hi = lo + winSize;
  const int base = (blockIdx.x >> 3) * 4096 + threadIdx.x;
  for (int t = 0; t < 16; ++t) {
    int i = base + t * 256;
    if (i < e) {
      int d = dst[i];
      if (d >= lo && d < hi) {
        int pos = atomicAdd(&cursor[d], 1);
        csr[pos] = src[i];
      }
    }
  }
}

// ---------------- dtype converts (once per launch) ----------------

__global__ __launch_bounds__(256) void cvt_f2h_k(const float* __restrict__ src,
                                                 __half* __restrict__ dst, int count4) {
  int i = blockIdx.x * 256 + threadIdx.x;
  if (i < count4) {
    float4 v = ((const float4*)src)[i];
    __half2 a = __floats2half2_rn(v.x, v.y);
    __half2 b = __floats2half2_rn(v.z, v.w);
    uint2 pk;
    pk.x = *(unsigned int*)&a;
    pk.y = *(unsigned int*)&b;
    ((uint2*)dst)[i] = pk;
  }
}

__global__ __launch_bounds__(256) void cvt_wt3_k(const float* __restrict__ W0,
                                                 const float* __restrict__ W1,
                                                 const float* __restrict__ W2,
                                                 __half* __restrict__ Wt0,
                                                 __half* __restrict__ Wt1,
                                                 __half* __restrict__ Wt2) {
  int i = blockIdx.x * 256 + threadIdx.x;
  if (i < 128 * 128) {
    int col = i >> 7, k = i & 127;
    Wt0[i] = __float2half(W0[k * 128 + col]);
    Wt1[i] = __float2half(W1[k * 128 + col]);
    if (col < 64) Wt2[(size_t)col * 128 + k] = __float2half(W2[k * 64 + col]);
  }
}

// ---------------- MFMA GEMM + fused attention dots ----------------

template<int M, int H_>
__global__ __launch_bounds__(256) void gemm_attn_mfma_k(const __half* __restrict__ Xh,
                                                        const __half* __restrict__ Wt,
                                                        const float* __restrict__ a_src,
                                                        const float* __restrict__ a_dst,
                                                        __half* __restrict__ Yh,
                                                        float* __restrict__ sArr,
                                                        float* __restrict__ dArr, int n) {
  constexpr int CT = M / 16;
  constexpr int LP = 136;  // LDS row pitch in halves (272B: 2-way conflict = free)
  __shared__ _Float16 Xs[64 * LP];
  __shared__ _Float16 Ws[M * LP];
  const int tid = threadIdx.x;
  const int w = tid >> 6;
  const int lane = tid & 63;
  const int l15 = lane & 15;
  const int quad = lane >> 4;
  const int rb = blockIdx.x * 64;

  for (int t = 0; t < 4; ++t) {
    int idx = tid + t * 256;
    int r = idx >> 4, c8 = idx & 15;
    uint4 v = make_uint4(0, 0, 0, 0);
    if (rb + r < n) v = *(const uint4*)(Xh + (size_t)(rb + r) * 128 + c8 * 8);
    *(uint4*)&Xs[r * LP + c8 * 8] = v;
  }
  for (int t = 0; t < CT; ++t) {
    int idx = tid + t * 256;
    int r = idx >> 4, c8 = idx & 15;
    *(uint4*)&Ws[r * LP + c8 * 8] = *(const uint4*)(Wt + (size_t)r * 128 + c8 * 8);
  }
  __syncthreads();

  floatx4 acc[CT];
  for (int c = 0; c < CT; ++c)
    for (int j = 0; j < 4; ++j) acc[c][j] = 0.f;

  const int arow = w * 16 + l15;
  for (int kq = 0; kq < 4; ++kq) {
    half8 a = *(const half8*)&Xs[arow * LP + kq * 32 + quad * 8];
    for (int c = 0; c < CT; ++c) {
      half8 b = *(const half8*)&Ws[(c * 16 + l15) * LP + kq * 32 + quad * 8];
      acc[c] = __builtin_amdgcn_mfma_f32_16x16x32_f16(a, b, acc[c], 0, 0, 0);
    }
  }

  float as[CT], ad[CT];
  for (int c = 0; c < CT; ++c) {
    as[c] = a_src[c * 16 + l15];
    ad[c] = a_dst[c * 16 + l15];
  }

  for (int c = 0; c < CT; ++c) {
    for (int r = 0; r < 4; ++r) {
      int row = rb + w * 16 + quad * 4 + r;
      if (row < n) Yh[(size_t)row * M + c * 16 + l15] = __float2half(acc[c][r]);
    }
  }

  for (int r = 0; r < 4; ++r) {
    int row = rb + w * 16 + quad * 4 + r;
    float s0 = 0.f, d0 = 0.f, s1 = 0.f, d1 = 0.f;
    if (H_ == 2) {
      for (int c = 0; c < CT / 2; ++c) {
        s0 += acc[c][r] * as[c];
        d0 += acc[c][r] * ad[c];
      }
      for (int c = CT / 2; c < CT; ++c) {
        s1 += acc[c][r] * as[c];
        d1 += acc[c][r] * ad[c];
      }
    } else {
      for (int c = 0; c < CT; ++c) {
        s0 += acc[c][r] * as[c];
        d0 += acc[c][r] * ad[c];
      }
    }
    for (int o = 1; o < 16; o <<= 1) {
      s0 += __shfl_xor(s0, o);
      d0 += __shfl_xor(d0, o);
      if (H_ == 2) {
        s1 += __shfl_xor(s1, o);
        d1 += __shfl_xor(d1, o);
      }
    }
    if (l15 == 0 && row < n) {
      if (H_ == 2) {
        sArr[row * 2] = s0;
        sArr[row * 2 + 1] = s1;
        dArr[row * 2] = d0;
        dArr[row * 2 + 1] = d1;
      } else {
        sArr[row] = s0;
        dArr[row] = d0;
      }
    }
  }
}

// ---------------- aggregation: TWO nodes per wave, 32 lanes each ----------------
// fp16 H=2 row = 256 B = 32 lanes x uint2(8B): half a wave covers a full row, so
// every instruction in the edge loop serves two edges (one per node). Degree
// mismatch between the pair is handled by the exec mask. Per-lane den sums its
// own node+head's weights over all its node's edges = that head's denominator.

__global__ __launch_bounds__(256) void edge2h_k(const __half* __restrict__ xlh,
                                                const float* __restrict__ sArr,
                                                const float* __restrict__ dArr,
                                                const float* __restrict__ bias,
                                                const int* __restrict__ row_ptr,
                                                const int* __restrict__ csr,
                                                __half* __restrict__ outh, int n) {
  const int wid = threadIdx.x >> 6;
  const int lane = threadIdx.x & 63;
  const int sub = lane >> 5;            // which node of the pair
  const int l32 = lane & 31;            // 8B unit within the 256B row
  const int node = blockIdx.x * 8 + wid * 2 + sub;
  if (node >= n) return;
  const int row = row_ptr[node];
  const int deg = row_ptr[node + 1] - row;
  const int head = l32 >> 4;            // halves [l32*4, l32*4+4) -> head = l32/16
  const uint2* __restrict__ xq = (const uint2*)xlh;   // row stride 32 units
  const float2 dn2 = ((const float2*)dArr)[node];
  const float dnsel = head ? dn2.y : dn2.x;
  float a0 = 0.f, a1 = 0.f, a2 = 0.f, a3 = 0.f;
  float den = 0.f;
  int j = 0;
  for (; j + 4 <= deg; j += 4) {
    int idx[4];
    float sv[4];
    uint2 p[4];
    for (int t = 0; t < 4; ++t) idx[t] = csr[row + j + t];
    for (int t = 0; t < 4; ++t) sv[t] = sArr[idx[t] * 2 + head];
    for (int t = 0; t < 4; ++t) p[t] = xq[(size_t)idx[t] * 32 + l32];
    for (int t = 0; t < 4; ++t) {
      float w = __expf(lrelu(sv[t] + dnsel));
      den += w;
      float2 v0 = __half22float2(*(__half2*)&p[t].x);
      float2 v1 = __half22float2(*(__half2*)&p[t].y);
      a0 += w * v0.x; a1 += w * v0.y; a2 += w * v1.x; a3 += w * v1.y;
    }
  }
  for (; j < deg; ++j) {
    int i0 = csr[row + j];
    float sv = sArr[i0 * 2 + head];
    uint2 p = xq[(size_t)i0 * 32 + l32];
    float w = __expf(lrelu(sv + dnsel));
    den += w;
    float2 v0 = __half22float2(*(__half2*)&p.x);
    float2 v1 = __half22float2(*(__half2*)&p.y);
    a0 += w * v0.x; a1 += w * v0.y; a2 += w * v1.x; a3 += w * v1.y;
  }
  // self loop
  float svS = sArr[node * 2 + head];
  uint2 pS = xq[(size_t)node * 32 + l32];
  float wS = __expf(lrelu(svS + dnsel));
  den += wS;
  {
    float2 v0 = __half22float2(*(__half2*)&pS.x);
    float2 v1 = __half22float2(*(__half2*)&pS.y);
    a0 += wS * v0.x; a1 += wS * v0.y; a2 += wS * v1.x; a3 += wS * v1.y;
  }

  float wi = 1.f / den;
  float4 bb = ((const float4*)bias)[l32];
  float r0 = a0 * wi + bb.x;
  float r1 = a1 * wi + bb.y;
  float r2 = a2 * wi + bb.z;
  float r3 = a3 * wi + bb.w;
  r0 = r0 > 0.f ? r0 : expm1f(r0);
  r1 = r1 > 0.f ? r1 : expm1f(r1);
  r2 = r2 > 0.f ? r2 : expm1f(r2);
  r3 = r3 > 0.f ? r3 : expm1f(r3);
  __half2 h0 = __floats2half2_rn(r0, r1);
  __half2 h1 = __floats2half2_rn(r2, r3);
  uint2 pk;
  pk.x = *(unsigned int*)&h0;
  pk.y = *(unsigned int*)&h1;
  ((uint2*)outh)[(size_t)node * 32 + l32] = pk;
}

// H=1: row = 64 halves = 128 B = 32 lanes x half2(4B); fp32 output (float2/lane).
__global__ __launch_bounds__(256) void edge1h_k(const __half* __restrict__ xlh,
                                                const float* __restrict__ sArr,
                                                const float* __restrict__ dArr,
                                                const float* __restrict__ bias,
                                                const int* __restrict__ row_ptr,
                                                const int* __restrict__ csr,
                                                float* __restrict__ outp, int n) {
  const int wid = threadIdx.x >> 6;
  const int lane = threadIdx.x & 63;
  const int sub = lane >> 5;
  const int l32 = lane & 31;
  const int node = blockIdx.x * 8 + wid * 2 + sub;
  if (node >= n) return;
  const int row = row_ptr[node];
  const int deg = row_ptr[node + 1] - row;
  const unsigned int* __restrict__ xq = (const unsigned int*)xlh;  // 4B units, stride 32
  const float dn = dArr[node];
  float a0 = 0.f, a1 = 0.f;
  float den = 0.f;
  int j = 0;
  for (; j + 4 <= deg; j += 4) {
    int idx[4];
    float sv[4];
    unsigned int p[4];
    for (int t = 0; t < 4; ++t) idx[t] = csr[row + j + t];
    for (int t = 0; t < 4; ++t) sv[t] = sArr[idx[t]];
    for (int t = 0; t < 4; ++t) p[t] = xq[(size_t)idx[t] * 32 + l32];
    for (int t = 0; t < 4; ++t) {
      float w = __expf(lrelu(sv[t] + dn));
      den += w;
      float2 v = __half22float2(*(__half2*)&p[t]);
      a0 += w * v.x; a1 += w * v.y;
    }
  }
  for (; j < deg; ++j) {
    int i0 = csr[row + j];
    float sv = sArr[i0];
    unsigned int p = xq[(size_t)i0 * 32 + l32];
    float w = __expf(lrelu(sv + dn));
    den += w;
    float2 v = __half22float2(*(__half2*)&p);
    a0 += w * v.x; a1 += w * v.y;
  }
  // self loop
  float wS = __expf(lrelu(sArr[node] + dn));
  unsigned int pS = xq[(size_t)node * 32 + l32];
  den += wS;
  {
    float2 v = __half22float2(*(__half2*)&pS);
    a0 += wS * v.x; a1 += wS * v.y;
  }

  float wi = 1.f / den;
  float2 bb = ((const float2*)bias)[l32];
  ((float2*)outp)[(size_t)node * 32 + l32] =
      make_float2(a0 * wi + bb.x, a1 * wi + bb.y);
}

// ---------------- launch ----------------

extern "C" void kernel_launch(void* const* d_in, const int* in_sizes, int n_in,
                              void* d_out, int out_size, void* d_ws, size_t ws_size,
                              hipStream_t stream) {
  const float* x  = (const float*)d_in[0];
  const int* ei   = (const int*)d_in[1];
  const float* W0 = (const float*)d_in[2];
  const float* as0 = (const float*)d_in[3];
  const float* ad0 = (const float*)d_in[4];
  const float* b0 = (const float*)d_in[5];
  const float* W1 = (const float*)d_in[6];
  const float* as1 = (const float*)d_in[7];
  const float* ad1 = (const float*)d_in[8];
  const float* b1 = (const float*)d_in[9];
  const float* W2 = (const float*)d_in[10];
  const float* as2 = (const float*)d_in[11];
  const float* ad2 = (const float*)d_in[12];
  const float* b2 = (const float*)d_in[13];
  float* out = (float*)d_out;

  const int n = in_sizes[0] / 128;
  const int e = in_sizes[1] / 2;
  const int* srcIdx = ei;
  const int* dstIdx = ei + e;

  float* ws = (float*)d_ws;
  float* sArr = ws;                                  // n*2
  float* dArr = sArr + (size_t)n * 2;                // n*2
  __half* xlh = (__half*)(dArr + (size_t)n * 2);     // n*128 halves
  __half* bufHh = xlh + (size_t)n * 128;             // n*128 halves
  __half* Wt0 = bufHh + (size_t)n * 128;             // 128*128
  __half* Wt1 = Wt0 + 128 * 128;                     // 128*128
  __half* Wt2 = Wt1 + 128 * 128;                     // 64*128
  int* csr = (int*)(Wt2 + 64 * 128);                 // e
  int* row_ptr = csr + e;                            // n+1
  int* cursor = row_ptr + (n + 1);                   // n
  int* blockSums = cursor + n;                       // nb

  const int nb = (n + 255) / 256;
  const int winSize = (n + 7) / 8;
  const int gwin = 8 * ((e + 4095) / 4096);

  cvt_wt3_k<<<(128 * 128 + 255) / 256, 256, 0, stream>>>(W0, W1, W2, Wt0, Wt1, Wt2);
  cvt_f2h_k<<<((n * 32) + 255) / 256, 256, 0, stream>>>(x, bufHh, n * 32);

  hipMemsetAsync(cursor, 0, (size_t)n * sizeof(int), stream);
  count_win_k<<<gwin, 256, 0, stream>>>(dstIdx, cursor, e, winSize);
  block_sum_k<<<nb, 256, 0, stream>>>(cursor, blockSums, n);
  scan_sums_k<<<1, 256, 0, stream>>>(blockSums, nb, row_ptr + n);
  scan_apply_k<<<nb, 256, 0, stream>>>(cursor, blockSums, row_ptr, n);
  scatter_win_k<<<gwin, 256, 0, stream>>>(srcIdx, dstIdx, cursor, csr, e, winSize);

  const int gb = (n + 63) / 64;
  const int gp = (n + 7) / 8;  // pair kernels: 8 nodes/block (4 waves x 2)

  // layer 0
  gemm_attn_mfma_k<128, 2><<<gb, 256, 0, stream>>>(bufHh, Wt0, as0, ad0, xlh, sArr, dArr, n);
  edge2h_k<<<gp, 256, 0, stream>>>(xlh, sArr, dArr, b0, row_ptr, csr, bufHh, n);

  // layer 1
  gemm_attn_mfma_k<128, 2><<<gb, 256, 0, stream>>>(bufHh, Wt1, as1, ad1, xlh, sArr, dArr, n);
  edge2h_k<<<gp, 256, 0, stream>>>(xlh, sArr, dArr, b1, row_ptr, csr, bufHh, n);

  // layer 2 (H=1, no concat, no elu, fp32 out)
  gemm_attn_mfma_k<64, 1><<<gb, 256, 0, stream>>>(bufHh, Wt2, as2, ad2, xlh, sArr, dArr, n);
  edge1h_k<<<gp, 256, 0, stream>>>(xlh, sArr, dArr, b2, row_ptr, csr, out, n);
}